// Round 6
// baseline (17792.754 us; speedup 1.0000x reference)
//
#include <hip/hip_runtime.h>
#include <cstddef>
#include <stdint.h>

// ---------------- problem constants ----------------
#define NHID 1024
#define NVOC 31
#define NB   64
#define NSEQ 512
#define NWRK 64      // 64 merged WGs: each owns 16 channels of BOTH layers
#define NGRID 256    // + 192 heater WGs (clock keep-alive; join epilogue)
#define NTHR 512     // 8 waves
#define EPSV 1e-5f
#define RS   68      // LDS reduce stride
#define SL   (NB*NHID)   // one h-state slot (128KB bf16)

typedef __attribute__((ext_vector_type(8))) short short8;   // 8 x bf16
typedef __attribute__((ext_vector_type(4))) float float4v;

// ---------------- sync area: 64B-strided flags (one line per WG) ----
#define OFF_F0  0               // 64 flags x 64B: step progress (f=k+2 <=> step k done)
#define OFF_FIN 8192            // end-of-recurrence counter (workers only)
#define CNT_BYTES 8256

// ---------------- MONO layout: write-once addresses -> plain cached reads ok
// y0b slot s = y0(s-1)  (slot0 = y0(-1) init), s=0..512
// y1s slot s = y1(s-1)  (slot0 = h1(-1) init), s=0..512  [old Y1+H1I regions fused]
#define M_OFF_Y0  8448
#define M_OFF_Y1  (M_OFF_Y0 + 513ull*SL*2)
#define M_OFF_T0  (M_OFF_Y1 + 513ull*SL*2)
#define M_OFF_ST  (M_OFF_T0 + 31ull*3*NHID*4)

// LDS: red + red2 = 2 x (192 rows x RS floats = 52224B) = 104448B -> 1 WG/CU
#define RED2_OFF  52224
#define LDS_BYTES 104448

__device__ __forceinline__ unsigned short f2bf(float f){
  unsigned u = __builtin_bit_cast(unsigned, f);
  u += 0x7fffu + ((u >> 16) & 1u);               // RNE
  return (unsigned short)(u >> 16);
}
__device__ __forceinline__ float bf2f(unsigned short h){
  unsigned u = ((unsigned)h) << 16;
  return __builtin_bit_cast(float, u);
}
__device__ __forceinline__ float sigm(float x){ return 1.f/(1.f + __expf(-x)); }
__device__ __forceinline__ float tanh_f(float x){ return 1.f - 2.f/(__expf(2.f*x) + 1.f); }

// dependent VALU chain (16 fmacs, ~64 cyc)
__device__ __forceinline__ void burn(float& d){
#pragma unroll
  for (int i=0;i<16;++i)
    asm volatile("v_fmac_f32 %0, %1, %2" : "+v"(d) : "v"(d), "v"(d));
}

// ---- flag sync: per-WG monotonic stores (64B-strided); wave-parallel polling
__device__ __forceinline__ void setflag(unsigned* f, unsigned v){
  __hip_atomic_store(f, v, __ATOMIC_RELAXED, __HIP_MEMORY_SCOPE_AGENT);
}
__device__ __forceinline__ void waitflags(const unsigned* f, int target, int lane, float& d){
  const unsigned* p = f + (size_t)lane*16;
  for(;;){
    int v = (int)__hip_atomic_load(p, __ATOMIC_RELAXED, __HIP_MEMORY_SCOPE_AGENT);
    if (__all(v >= target)) break;
    burn(d);
  }
  asm volatile("" ::: "memory");   // block hoisting dependent loads above the wait
}
__device__ __forceinline__ void sig(unsigned* c){
  __hip_atomic_fetch_add(c, 1u, __ATOMIC_RELAXED, __HIP_MEMORY_SCOPE_AGENT);
}
__device__ __forceinline__ void waitc(unsigned* c, unsigned v, float& d){
  while (__hip_atomic_load(c, __ATOMIC_RELAXED, __HIP_MEMORY_SCOPE_AGENT) < v)
    burn(d);
}

// sc1 = write past the non-coherent per-XCD L2 to the device coherence point.
// (R4 proved sc0 alone leaves data stranded in the producer XCD's L2.)
__device__ __forceinline__ void stc16(void* p, short8 v){
  asm volatile("global_store_dwordx4 %0, %1, off sc1"
               :: "v"((unsigned long long)(uintptr_t)p), "v"(v) : "memory");
}
__device__ __forceinline__ void drain_vm(){
  asm volatile("s_waitcnt vmcnt(0)" ::: "memory");
}
__device__ __forceinline__ void stc16_drain(void* p, short8 v){
  stc16(p, v); drain_vm();
}

// plain cached fragment loads (mono addresses are write-once -> never stale)
__device__ __forceinline__ void load_a16_plain(const unsigned short* base, short8 (&f)[4][4]){
#pragma unroll
  for (int r=0;r<4;++r){
    const short8* p = (const short8*)(base + (size_t)r*16*NHID);
#pragma unroll
    for (int kt=0;kt<4;++kt) f[r][kt] = p[kt*4];
  }
}

// two-stage cross-wave reduce helpers operate inline below (need dual buffers)

__device__ __forceinline__ void load_bfrags(const float* W, const int* rowbase,
                                            short8 (&bfr)[3][4], int lane, int wid)
{
  const int l15 = lane & 15, q = lane >> 4;
#pragma unroll
  for (int nt=0; nt<3; ++nt){
    const float* wp0 = W + (size_t)(rowbase[nt] + l15)*NHID + wid*128 + q*8;
#pragma unroll
    for (int kt=0; kt<4; ++kt){
      const float* wp = wp0 + kt*32;
      short8 fr;
#pragma unroll
      for (int j=0;j<8;++j) fr[j] = (short)f2bf(wp[j]);
      bfr[nt][kt] = fr;
    }
  }
}

// single-buffer gemm (phase2: Whh1) — identical to baseline gemm_frags
__device__ __forceinline__ void gemm_frags(const short8 (&f)[4][4],
                                           const short8 (&bfr)[3][4],
                                           float* red, int lane, int wid)
{
  const int l15 = lane & 15, q = lane >> 4;
  float4v acc[4][3];
#pragma unroll
  for (int mt=0; mt<4; ++mt)
#pragma unroll
    for (int nt=0; nt<3; ++nt) acc[mt][nt] = (float4v){0.f,0.f,0.f,0.f};
#pragma unroll
  for (int kt=0; kt<4; ++kt){
#pragma unroll
    for (int nt=0; nt<3; ++nt){
      acc[0][nt] = __builtin_amdgcn_mfma_f32_16x16x32_bf16(f[0][kt], bfr[nt][kt], acc[0][nt],0,0,0);
      acc[1][nt] = __builtin_amdgcn_mfma_f32_16x16x32_bf16(f[1][kt], bfr[nt][kt], acc[1][nt],0,0,0);
      acc[2][nt] = __builtin_amdgcn_mfma_f32_16x16x32_bf16(f[2][kt], bfr[nt][kt], acc[2][nt],0,0,0);
      acc[3][nt] = __builtin_amdgcn_mfma_f32_16x16x32_bf16(f[3][kt], bfr[nt][kt], acc[3][nt],0,0,0);
    }
  }
  if (wid >= 4){
#pragma unroll
    for (int mt=0; mt<4; ++mt)
#pragma unroll
      for (int nt=0; nt<3; ++nt){
        int n = nt*16 + l15, row = mt*16 + q*4;
        *(float4v*)(red + ((wid-4)*48 + n)*RS + row) = acc[mt][nt];
      }
  }
  __syncthreads();
  if (wid < 4){
#pragma unroll
    for (int mt=0; mt<4; ++mt)
#pragma unroll
      for (int nt=0; nt<3; ++nt){
        int n = nt*16 + l15, row = mt*16 + q*4;
        float4v* p = (float4v*)(red + (wid*48 + n)*RS + row);
        float4v v = *p;
        *p = v + acc[mt][nt];
      }
  }
  __syncthreads();
}

__global__ __launch_bounds__(NTHR, 2) void mgru_fused(
    const int*   __restrict__ x,    const float* __restrict__ h0,
    const float* __restrict__ emb,
    const float* __restrict__ Wih0, const float* __restrict__ Whh0,
    const float* __restrict__ bih0, const float* __restrict__ bhh0,
    const float* __restrict__ Wih1, const float* __restrict__ Whh1,
    const float* __restrict__ bih1, const float* __restrict__ bhh1,
    const float* __restrict__ gamma, const float* __restrict__ beta,
    const float* __restrict__ Wout, const float* __restrict__ bout,
    float* __restrict__ out, char* ws)
{
  __shared__ __align__(16) char smem[LDS_BYTES];
  float* red  = (float*)smem;
  float* red2 = (float*)(smem + RED2_OFF);

  unsigned* f0  = (unsigned*)(ws + OFF_F0);
  unsigned* fin = (unsigned*)(ws + OFF_FIN);
  unsigned short* y0b   = (unsigned short*)(ws + M_OFF_Y0);
  unsigned short* y1s   = (unsigned short*)(ws + M_OFF_Y1);
  float*          T0    = (float*)(ws + M_OFF_T0);
  float*          stats = (float*)(ws + M_OFF_ST);

  const int tid  = threadIdx.x;
  const int lane = tid & 63;
  const int wid  = tid >> 6;
  const int wg   = blockIdx.x;
  const int l15 = lane & 15, q = lane >> 4;
  float dummy = (float)tid * 1e-30f + 1.0f;

  if (wg >= NWRK){
    // ============ heater: keep DPM/clocks boosted; then join epilogue ====
    for(;;){
      for (int i=0;i<64;++i) burn(dummy);   // ~4K dependent cycles
      unsigned v = __hip_atomic_load(fin, __ATOMIC_RELAXED, __HIP_MEMORY_SCOPE_AGENT);
      if (v >= (unsigned)NWRK) break;
    }
    if (tid == 0) __threadfence();          // acquire: see y1/stats
    __syncthreads();
    if (dummy == 1234.5678f) ((volatile float*)smem)[0] = dummy;
    goto epilogue;
  }

  {
    const int sub = wg;
    const int ch0 = sub*16;
    const int cg  = tid >> 6;       // gate threads: tid<128 -> cg in {0,1}
    const int gb  = tid & 63;
    int rowbase[3] = {ch0, NHID + ch0, 2*NHID + ch0};

    // one-time acquire: invalidate stale lines from a previous launch
    if (tid == 0) __threadfence();
    __syncthreads();

    // ====== merged single chain: step t computes y0(t) AND y1(t-1) ======
    // All inputs of step t were published at step t-1 -> ONE flag wait,
    // ONE publish+drain, ONE all-to-all per step (baseline had two coupled
    // chains paying the MALL hop toll each). gemmA0/gemmB1 share A-frags.
    short8 bfr0[3][4], wf[3][4], bfrH[3][4];
    float hprev0[8] = {0,0,0,0,0,0,0,0};
    float hprev1[8] = {0,0,0,0,0,0,0,0};
    float br[8], bz[8], bn[8];
    float s1[8] = {0,0,0,0,0,0,0,0}, s2[8] = {0,0,0,0,0,0,0,0};

    if (tid < 128){
      short8 pk0, pk1;
#pragma unroll
      for (int j=0;j<8;++j){
        int c = ch0 + cg*8 + j;
        hprev0[j] = h0[(size_t)gb*NHID + c];
        hprev1[j] = h0[(size_t)NB*NHID + (size_t)gb*NHID + c];
        br[j] = bhh0[c]; bz[j] = bhh0[NHID + c]; bn[j] = bhh0[2*NHID + c];
        pk0[j] = (short)f2bf(hprev0[j]);
        pk1[j] = (short)f2bf(hprev1[j]);
      }
      stc16(y0b + (size_t)gb*NHID + ch0 + cg*8, pk0);   // slot0 = y0(-1)
      stc16(y1s + (size_t)gb*NHID + ch0 + cg*8, pk1);   // slot0 = y1(-1)
      drain_vm();
    }
    __syncthreads();
    if (tid == 0) setflag(f0 + (size_t)wg*16, 1u);

    // T0 slice (WG-private, plain cached)
    for (int e = tid; e < NVOC*48; e += NTHR){
      int v = e / 48, n = e - v*48;
      int g = (n<16) ? (ch0+n) : (n<32 ? (NHID+ch0+n-16) : (2*NHID+ch0+n-32));
      const float4v* e4 = (const float4v*)(emb  + (size_t)v*NHID);
      const float4v* w4 = (const float4v*)(Wih0 + (size_t)g*NHID);
      float acc = 0.f;
      for (int k=0;k<NHID/4;++k){
        float4v a = e4[k], bb = w4[k];
        acc += a[0]*bb[0] + a[1]*bb[1] + a[2]*bb[2] + a[3]*bb[3];
      }
      T0[(size_t)v*3*NHID + g] = acc + bih0[g];
    }
    load_bfrags(Whh0, rowbase, bfr0, lane, wid);
    load_bfrags(Wih1, rowbase, wf,   lane, wid);
    load_bfrags(Whh1, rowbase, bfrH, lane, wid);
    __syncthreads();

    for (int t = 0; t <= NSEQ; ++t){
      waitflags(f0, t+1, lane, dummy);   // step t-1 done: y0(t-1), y1(t-2) ready

      // ---- phase1: dual gemm on shared A-frags fA = y0(t-1) ----
      short8 fA[4][4];
      load_a16_plain(y0b + (size_t)t*SL + (size_t)l15*NHID + wid*128 + q*8, fA);
      float4v acc[4][3], accX[4][3];
#pragma unroll
      for (int mt=0; mt<4; ++mt)
#pragma unroll
        for (int nt=0; nt<3; ++nt){ acc[mt][nt] = (float4v){0,0,0,0}; accX[mt][nt] = (float4v){0,0,0,0}; }
#pragma unroll
      for (int kt=0; kt<4; ++kt){
#pragma unroll
        for (int nt=0; nt<3; ++nt){
          acc[0][nt]  = __builtin_amdgcn_mfma_f32_16x16x32_bf16(fA[0][kt], bfr0[nt][kt], acc[0][nt],0,0,0);
          acc[1][nt]  = __builtin_amdgcn_mfma_f32_16x16x32_bf16(fA[1][kt], bfr0[nt][kt], acc[1][nt],0,0,0);
          acc[2][nt]  = __builtin_amdgcn_mfma_f32_16x16x32_bf16(fA[2][kt], bfr0[nt][kt], acc[2][nt],0,0,0);
          acc[3][nt]  = __builtin_amdgcn_mfma_f32_16x16x32_bf16(fA[3][kt], bfr0[nt][kt], acc[3][nt],0,0,0);
          accX[0][nt] = __builtin_amdgcn_mfma_f32_16x16x32_bf16(fA[0][kt], wf[nt][kt], accX[0][nt],0,0,0);
          accX[1][nt] = __builtin_amdgcn_mfma_f32_16x16x32_bf16(fA[1][kt], wf[nt][kt], accX[1][nt],0,0,0);
          accX[2][nt] = __builtin_amdgcn_mfma_f32_16x16x32_bf16(fA[2][kt], wf[nt][kt], accX[2][nt],0,0,0);
          accX[3][nt] = __builtin_amdgcn_mfma_f32_16x16x32_bf16(fA[3][kt], wf[nt][kt], accX[3][nt],0,0,0);
        }
      }
      // prefetch phase2 A-frags (y1(t-2)) while reduce+gates0 run
      short8 fH[4][4];
      if (t >= 1)
        load_a16_plain(y1s + (size_t)(t-1)*SL + (size_t)l15*NHID + wid*128 + q*8, fH);

      if (wid >= 4){
#pragma unroll
        for (int mt=0; mt<4; ++mt)
#pragma unroll
          for (int nt=0; nt<3; ++nt){
            int n = nt*16 + l15, row = mt*16 + q*4;
            *(float4v*)(red  + ((wid-4)*48 + n)*RS + row) = acc[mt][nt];
            *(float4v*)(red2 + ((wid-4)*48 + n)*RS + row) = accX[mt][nt];
          }
      }
      __syncthreads();
      if (wid < 4){
#pragma unroll
        for (int mt=0; mt<4; ++mt)
#pragma unroll
          for (int nt=0; nt<3; ++nt){
            int n = nt*16 + l15, row = mt*16 + q*4;
            float4v* p1 = (float4v*)(red  + (wid*48 + n)*RS + row);
            float4v* p2 = (float4v*)(red2 + (wid*48 + n)*RS + row);
            float4v v1 = *p1, v2 = *p2;
            *p1 = v1 + acc[mt][nt];
            *p2 = v2 + accX[mt][nt];
          }
      }
      __syncthreads();

      // ---- gates0: y0(t) (skip at t==NSEQ) ----
      if (t < NSEQ && tid < 128){
        int tok = x[(size_t)gb*NSEQ + t];
        const float* tr = T0 + (size_t)tok*3*NHID + ch0 + cg*8;
        short8 pk;
#pragma unroll
        for (int j=0;j<8;++j){
          float hr = br[j], hz = bz[j], hn = bn[j];
#pragma unroll
          for (int w=0;w<4;++w){
            hr += red[(w*48 +      cg*8 + j)*RS + gb];
            hz += red[(w*48 + 16 + cg*8 + j)*RS + gb];
            hn += red[(w*48 + 32 + cg*8 + j)*RS + gb];
          }
          float r = sigm(tr[j] + hr);
          float z = sigm(tr[NHID + j] + hz);
          float n = tanh_f(tr[2*NHID + j] + r*hn);
          float hnv = (1.f - z)*n + z*hprev0[j];
          hprev0[j] = hnv;
          pk[j] = (short)f2bf(hnv);
        }
        stc16(y0b + (size_t)(t+1)*SL + (size_t)gb*NHID + ch0 + cg*8, pk);  // drained below
      }
      __syncthreads();   // red WAR: gates0 reads done before gemmA1 overwrites

      // ---- phase2: gemmA1 (Whh1 x y1(t-2)) + gates1 -> y1(t-1) (t>=1) ----
      if (t >= 1){
        gemm_frags(fH, bfrH, red, lane, wid);
        if (tid < 128){
          short8 pk;
#pragma unroll
          for (int j=0;j<8;++j){
            int c = ch0 + cg*8 + j;
            float hr = bhh1[c], hz = bhh1[NHID + c], hn = bhh1[2*NHID + c];
            float xr = bih1[c], xz = bih1[NHID + c], xn = bih1[2*NHID + c];
#pragma unroll
            for (int w=0;w<4;++w){
              hr += red [(w*48 +      cg*8 + j)*RS + gb];
              hz += red [(w*48 + 16 + cg*8 + j)*RS + gb];
              hn += red [(w*48 + 32 + cg*8 + j)*RS + gb];
              xr += red2[(w*48 +      cg*8 + j)*RS + gb];
              xz += red2[(w*48 + 16 + cg*8 + j)*RS + gb];
              xn += red2[(w*48 + 32 + cg*8 + j)*RS + gb];
            }
            float r  = sigm(xr + hr);
            float z  = sigm(xz + hz);
            float nn = tanh_f(xn + r*hn);
            float hnew = (1.f - z)*nn + z*hprev1[j];
            hprev1[j] = hnew;
            unsigned short hb = f2bf(hnew);
            pk[j] = (short)hb;
            float hq = bf2f(hb);             // BN stats from stored bf16
            s1[j] += hq; s2[j] += hq*hq;
          }
          stc16(y1s + (size_t)t*SL + (size_t)gb*NHID + ch0 + cg*8, pk);  // slot t = y1(t-1)
        }
      }
      drain_vm();                            // one drain covers y0 + y1 stores
      __syncthreads();
      if (tid == 0) setflag(f0 + (size_t)wg*16, (unsigned)(t+2));
    }

    // BN stats fold (each WG owns its 16 channels)
    {
      float* sb = (float*)smem;
      __syncthreads();
      if (tid < 128){
#pragma unroll
        for (int j=0;j<8;++j) sb[(cg*8 + j)*64 + gb] = s1[j];
      }
      __syncthreads();
      if (tid < 16){
        float a = 0.f;
        for (int i=0;i<64;++i) a += sb[tid*64 + i];
        stats[ch0 + tid] = a;
      }
      __syncthreads();
      if (tid < 128){
#pragma unroll
        for (int j=0;j<8;++j) sb[(cg*8 + j)*64 + gb] = s2[j];
      }
      __syncthreads();
      if (tid < 16){
        float a = 0.f;
        for (int i=0;i<64;++i) a += sb[tid*64 + i];
        stats[NHID + ch0 + tid] = a;
      }
    }

    // ======== fin barrier with ONE wbL2/inv fence pair per WG ========
    __syncthreads();
    if (tid == 0){
      __threadfence();          // release: writeback dirty L2 (y1/stats)
      sig(fin);
      waitc(fin, NWRK, dummy);
      __threadfence();          // acquire
    }
    __syncthreads();
    if (dummy == 1234.5678f) ((volatile float*)smem)[0] = dummy;  // keep alive
  }

epilogue:
  // ================= epilogue: fold BN into Wout, GEMM -> out =================
  {
    const float inv_n = 1.f/32768.f;

    float* bpart    = (float*)smem;
    float* bprime_l = (float*)(smem + 2048);
    {
      int v = tid >> 4, k0 = tid & 15;
      float partial = 0.f;
      if (v < NVOC){
        for (int k = k0; k < NHID; k += 16){
          float mu  = stats[k]*inv_n;
          float var = stats[NHID+k]*inv_n - mu*mu;
          float sc  = gamma[k]*rsqrtf(var + EPSV);
          partial += (beta[k] - mu*sc) * Wout[(size_t)v*NHID + k];
        }
      }
      bpart[tid] = partial;
    }
    __syncthreads();
    if (tid < 32){
      float bpv = 0.f;
      for (int j=0;j<16;++j) bpv += bpart[tid*16 + j];
      bprime_l[tid] = (tid < NVOC) ? (bpv + bout[tid]) : 0.f;
    }
    __syncthreads();
    float bp_a = bprime_l[l15];
    float bp_b = (l15 < 15) ? bprime_l[16 + l15] : 0.f;
    __syncthreads();

    unsigned short* wsc = (unsigned short*)smem;   // [31][1032] bf16
    for (int e = tid; e < NVOC*1032; e += NTHR){
      int v = e / 1032, k = e - v*1032;
      float val = 0.f;
      if (k < NHID){
        float mu  = stats[k]*inv_n;
        float var = stats[NHID+k]*inv_n - mu*mu;
        float sc  = gamma[k]*rsqrtf(var + EPSV);
        val = Wout[(size_t)v*NHID + k] * sc;
      }
      wsc[e] = f2bf(val);
    }
    __syncthreads();

    unsigned short* y1d = (unsigned short*)(ws + M_OFF_Y1) + SL;  // slot1 = y1(0)
    int wglob = wg*8 + wid;                 // 0..2047 over 256 WGs
    if ((wglob & 3) == 0){
      int J = wglob >> 2;         // 0..511
      float4v acc[4][2];
#pragma unroll
      for (int mt=0;mt<4;++mt){ acc[mt][0] = (float4v){0,0,0,0}; acc[mt][1] = (float4v){0,0,0,0}; }
      const unsigned short* abase = y1d + (size_t)(J*64 + l15)*NHID + q*8;
      const short8 zero8 = (short8){0,0,0,0,0,0,0,0};
#pragma unroll 4
      for (int kt=0; kt<32; ++kt){
        short8 bv0 = *(const short8*)(wsc + (size_t)l15*1032 + kt*32 + q*8);
        short8 bv1 = (l15 < 15) ? *(const short8*)(wsc + (size_t)(16+l15)*1032 + kt*32 + q*8) : zero8;
        short8 a0 = *(const short8*)(abase + (size_t)kt*32);
        short8 a1 = *(const short8*)(abase + 16*NHID + (size_t)kt*32);
        short8 a2 = *(const short8*)(abase + 32*NHID + (size_t)kt*32);
        short8 a3 = *(const short8*)(abase + 48*NHID + (size_t)kt*32);
        acc[0][0] = __builtin_amdgcn_mfma_f32_16x16x32_bf16(a0, bv0, acc[0][0],0,0,0);
        acc[1][0] = __builtin_amdgcn_mfma_f32_16x16x32_bf16(a1, bv0, acc[1][0],0,0,0);
        acc[2][0] = __builtin_amdgcn_mfma_f32_16x16x32_bf16(a2, bv0, acc[2][0],0,0,0);
        acc[3][0] = __builtin_amdgcn_mfma_f32_16x16x32_bf16(a3, bv0, acc[3][0],0,0,0);
        acc[0][1] = __builtin_amdgcn_mfma_f32_16x16x32_bf16(a0, bv1, acc[0][1],0,0,0);
        acc[1][1] = __builtin_amdgcn_mfma_f32_16x16x32_bf16(a1, bv1, acc[1][1],0,0,0);
        acc[2][1] = __builtin_amdgcn_mfma_f32_16x16x32_bf16(a2, bv1, acc[2][1],0,0,0);
        acc[3][1] = __builtin_amdgcn_mfma_f32_16x16x32_bf16(a3, bv1, acc[3][1],0,0,0);
      }
#pragma unroll
      for (int mt=0;mt<4;++mt){
#pragma unroll
        for (int nt=0;nt<2;++nt){
          int v = nt*16 + l15;
          if (v < NVOC){
            float bpv = (nt==0) ? bp_a : bp_b;
            int r0 = J*64 + mt*16 + q*4;
#pragma unroll
            for (int i2=0;i2<4;++i2){
              int r = r0 + i2;
              int b = r & 63, tt = r >> 6;
              out[(size_t)(b*NSEQ + tt)*NVOC + v] = acc[mt][nt][i2] + bpv;
            }
          }
        }
      }
    }
  }
}

extern "C" void kernel_launch(void* const* d_in, const int* in_sizes, int n_in,
                              void* d_out, int out_size, void* d_ws, size_t ws_size,
                              hipStream_t stream) {
  (void)in_sizes; (void)n_in; (void)out_size; (void)ws_size;
  hipMemsetAsync(d_ws, 0, CNT_BYTES, stream);   // zero flags + fin counter
  mgru_fused<<<dim3(NGRID), dim3(NTHR), 0, stream>>>(
      (const int*)d_in[0],  (const float*)d_in[1],  (const float*)d_in[2],
      (const float*)d_in[3], (const float*)d_in[4], (const float*)d_in[5],
      (const float*)d_in[6], (const float*)d_in[7], (const float*)d_in[8],
      (const float*)d_in[9], (const float*)d_in[10], (const float*)d_in[11],
      (const float*)d_in[12], (const float*)d_in[13], (const float*)d_in[14],
      (float*)d_out, (char*)d_ws);
}

// Round 7
// 4171.058 us; speedup vs baseline: 4.2658x; 4.2658x over previous
//
#include <hip/hip_runtime.h>
#include <cstddef>
#include <stdint.h>

// ---------------- problem constants ----------------
#define NHID 1024
#define NVOC 31
#define NB   64
#define NSEQ 512
#define NWRK 192     // 64 role0 (L0, 2D) + 64 role1 (xg, 1D) + 64 role2 (L1, 2D)
#define NGRID 256    // + 64 heater WGs
#define NTHR 512     // 8 waves
#define EPSV 1e-5f
#define RS   68      // role1 LDS reduce stride (baseline layout, 192x68)
#define RS2  36      // 2D LDS reduce stride (384 rows x 36)
#define SL   (NB*NHID)   // one h-state slot (128KB bf16)
#define XG_SLOTS 16

typedef __attribute__((ext_vector_type(8))) short short8;   // 8 x bf16
typedef __attribute__((ext_vector_type(4))) float float4v;

// ---------------- sync area: 64B-strided flags (one line per WG) ----
#define OFF_F0  0               // 64 flags: role0 (idx bg*32+cg); f=t+2 <=> step t done
#define OFF_F1  4096            // 64 flags: role1 subs (xg published)
#define OFF_F2  8192            // 64 flags: role2 (idx bg*32+cg)
#define OFF_FIN 12288
#define CNT_BYTES 12352

// ---------------- MONO layout: write-once addresses -> plain cached reads ok
#define M_OFF_Y0  12544                             // 513 slots: slot t+1 = y0(t)
#define M_OFF_Y1  (M_OFF_Y0 + 513ull*SL*2)          // 512 slots: y1(t)
#define M_OFF_H1I (M_OFF_Y1 + 512ull*SL*2)          // h1(-1)
#define M_OFF_T0  (M_OFF_H1I + (unsigned long long)SL*2)
#define M_OFF_ST  (M_OFF_T0 + 31ull*3*NHID*4)       // statsP[2 bg][2][1024] f32
#define M_OFF_XG  (M_OFF_ST + 16384ull)             // ring: 16 x 64 x 3072 f32

// LDS: 2D red = 384*36*4 = 55296; role1 red = 192*68*4 = 52224; wsc = 63984
#define LDS_BYTES 65024

__device__ __forceinline__ unsigned short f2bf(float f){
  unsigned u = __builtin_bit_cast(unsigned, f);
  u += 0x7fffu + ((u >> 16) & 1u);               // RNE
  return (unsigned short)(u >> 16);
}
__device__ __forceinline__ float bf2f(unsigned short h){
  unsigned u = ((unsigned)h) << 16;
  return __builtin_bit_cast(float, u);
}
__device__ __forceinline__ float sigm(float x){ return 1.f/(1.f + __expf(-x)); }
__device__ __forceinline__ float tanh_f(float x){ return 1.f - 2.f/(__expf(2.f*x) + 1.f); }

__device__ __forceinline__ void burn(float& d){
#pragma unroll
  for (int i=0;i<16;++i)
    asm volatile("v_fmac_f32 %0, %1, %2" : "+v"(d) : "v"(d), "v"(d));
}

// ---- flag sync ----
__device__ __forceinline__ void setflag(unsigned* f, unsigned v){
  __hip_atomic_store(f, v, __ATOMIC_RELAXED, __HIP_MEMORY_SCOPE_AGENT);
}
__device__ __forceinline__ void waitflags64(const unsigned* f, int target, int lane, float& d){
  const unsigned* p = f + (size_t)lane*16;
  for(;;){
    int v = (int)__hip_atomic_load(p, __ATOMIC_RELAXED, __HIP_MEMORY_SCOPE_AGENT);
    if (__all(v >= target)) break;
    burn(d);
  }
  asm volatile("" ::: "memory");
}
__device__ __forceinline__ void waitflags32(const unsigned* f, int base32, int target, int lane, float& d){
  const unsigned* p = f + (size_t)(base32 + (lane & 31))*16;
  for(;;){
    int v = (int)__hip_atomic_load(p, __ATOMIC_RELAXED, __HIP_MEMORY_SCOPE_AGENT);
    if (__all(v >= target)) break;
    burn(d);
  }
  asm volatile("" ::: "memory");
}
__device__ __forceinline__ void waitflags2(const unsigned* f, int base2, int target, int lane, float& d){
  const unsigned* p = f + (size_t)(base2 + (lane & 1))*16;
  for(;;){
    int v = (int)__hip_atomic_load(p, __ATOMIC_RELAXED, __HIP_MEMORY_SCOPE_AGENT);
    if (__all(v >= target)) break;
    burn(d);
  }
  asm volatile("" ::: "memory");
}
__device__ __forceinline__ void waitflags_slow64(const unsigned* f, int target, int lane, float& d){
  const unsigned* p = f + (size_t)lane*16;
  for(;;){
    int v = (int)__hip_atomic_load(p, __ATOMIC_RELAXED, __HIP_MEMORY_SCOPE_AGENT);
    if (__all(v >= target)) break;
    burn(d); burn(d); burn(d); burn(d);
  }
  asm volatile("" ::: "memory");
}
__device__ __forceinline__ void sig(unsigned* c){
  __hip_atomic_fetch_add(c, 1u, __ATOMIC_RELAXED, __HIP_MEMORY_SCOPE_AGENT);
}
__device__ __forceinline__ void waitc(unsigned* c, unsigned v, float& d){
  while (__hip_atomic_load(c, __ATOMIC_RELAXED, __HIP_MEMORY_SCOPE_AGENT) < v)
    burn(d);
}

// sc1: write past the non-coherent per-XCD L2 (R4 proved sc0 breaks)
__device__ __forceinline__ void stc16(void* p, short8 v){
  asm volatile("global_store_dwordx4 %0, %1, off sc1"
               :: "v"((unsigned long long)(uintptr_t)p), "v"(v) : "memory");
}
__device__ __forceinline__ void stc4(void* p, float v){
  asm volatile("global_store_dword %0, %1, off sc1"
               :: "v"((unsigned long long)(uintptr_t)p), "v"(v) : "memory");
}
__device__ __forceinline__ void drain_vm(){
  asm volatile("s_waitcnt vmcnt(0)" ::: "memory");
}

// ---- baseline 1D machinery (role1) ----
__device__ __forceinline__ void load_a16_plain(const unsigned short* base, short8 (&f)[4][4]){
#pragma unroll
  for (int r=0;r<4;++r){
    const short8* p = (const short8*)(base + (size_t)r*16*NHID);
#pragma unroll
    for (int kt=0;kt<4;++kt) f[r][kt] = p[kt*4];
  }
}
__device__ __forceinline__ void gemm_frags(const short8 (&f)[4][4],
                                           const short8 (&bfr)[3][4],
                                           float* red, int lane, int wid)
{
  const int l15 = lane & 15, q = lane >> 4;
  float4v acc[4][3];
#pragma unroll
  for (int mt=0; mt<4; ++mt)
#pragma unroll
    for (int nt=0; nt<3; ++nt) acc[mt][nt] = (float4v){0.f,0.f,0.f,0.f};
#pragma unroll
  for (int kt=0; kt<4; ++kt){
#pragma unroll
    for (int nt=0; nt<3; ++nt){
      acc[0][nt] = __builtin_amdgcn_mfma_f32_16x16x32_bf16(f[0][kt], bfr[nt][kt], acc[0][nt],0,0,0);
      acc[1][nt] = __builtin_amdgcn_mfma_f32_16x16x32_bf16(f[1][kt], bfr[nt][kt], acc[1][nt],0,0,0);
      acc[2][nt] = __builtin_amdgcn_mfma_f32_16x16x32_bf16(f[2][kt], bfr[nt][kt], acc[2][nt],0,0,0);
      acc[3][nt] = __builtin_amdgcn_mfma_f32_16x16x32_bf16(f[3][kt], bfr[nt][kt], acc[3][nt],0,0,0);
    }
  }
  if (wid >= 4){
#pragma unroll
    for (int mt=0; mt<4; ++mt)
#pragma unroll
      for (int nt=0; nt<3; ++nt){
        int n = nt*16 + l15, row = mt*16 + q*4;
        *(float4v*)(red + ((wid-4)*48 + n)*RS + row) = acc[mt][nt];
      }
  }
  __syncthreads();
  if (wid < 4){
#pragma unroll
    for (int mt=0; mt<4; ++mt)
#pragma unroll
      for (int nt=0; nt<3; ++nt){
        int n = nt*16 + l15, row = mt*16 + q*4;
        float4v* p = (float4v*)(red + (wid*48 + n)*RS + row);
        float4v v = *p;
        *p = v + acc[mt][nt];
      }
  }
  __syncthreads();
}
__device__ __forceinline__ void load_bfrags(const float* W, const int* rowbase,
                                            short8 (&bfr)[3][4], int lane, int wid)
{
  const int l15 = lane & 15, q = lane >> 4;
#pragma unroll
  for (int nt=0; nt<3; ++nt){
    const float* wp0 = W + (size_t)(rowbase[nt] + l15)*NHID + wid*128 + q*8;
#pragma unroll
    for (int kt=0; kt<4; ++kt){
      const float* wp = wp0 + kt*32;
      short8 fr;
#pragma unroll
      for (int j=0;j<8;++j) fr[j] = (short)f2bf(wp[j]);
      bfr[nt][kt] = fr;
    }
  }
}

// ---- 2D machinery (role0 / role2): WG owns 32 batches x 32 channels ----
// weight B-frags: 6 n-tiles; n-index in red = gate*32 + c32
__device__ __forceinline__ void load_bfrags6(const float* W, int ch0,
                                             short8 (&bfr)[6][4], int lane, int wid)
{
  const int l15 = lane & 15, q = lane >> 4;
#pragma unroll
  for (int nt=0; nt<6; ++nt){
    int grow = (nt>>1)*NHID + ch0 + (nt&1)*16 + l15;
    const float* wp0 = W + (size_t)grow*NHID + wid*128 + q*8;
#pragma unroll
    for (int kt=0; kt<4; ++kt){
      const float* wp = wp0 + kt*32;
      short8 fr;
#pragma unroll
      for (int j=0;j<8;++j) fr[j] = (short)f2bf(wp[j]);
      bfr[nt][kt] = fr;
    }
  }
}
__device__ __forceinline__ void load_a2(const unsigned short* slab, int b0,
                                        short8 (&f)[2][4], int lane, int wid)
{
#pragma unroll
  for (int mt=0;mt<2;++mt){
    const short8* p = (const short8*)(slab + (size_t)(b0 + mt*16 + (lane&15))*NHID
                                      + wid*128 + (lane>>4)*8);
#pragma unroll
    for (int kt=0;kt<4;++kt) f[mt][kt] = p[kt*4];
  }
}
// M=32,N=96,K=1024: 8 waves split K 8-way; pair-reduce (w, w+4) like baseline
__device__ __forceinline__ void gemm2d(const short8 (&fA)[2][4],
                                       const short8 (&bfr)[6][4],
                                       float* red, int lane, int wid)
{
  const int l15 = lane & 15, q = lane >> 4;
  float4v acc[2][6];
#pragma unroll
  for (int mt=0; mt<2; ++mt)
#pragma unroll
    for (int nt=0; nt<6; ++nt) acc[mt][nt] = (float4v){0.f,0.f,0.f,0.f};
#pragma unroll
  for (int kt=0; kt<4; ++kt){
#pragma unroll
    for (int nt=0; nt<6; ++nt){
      acc[0][nt] = __builtin_amdgcn_mfma_f32_16x16x32_bf16(fA[0][kt], bfr[nt][kt], acc[0][nt],0,0,0);
      acc[1][nt] = __builtin_amdgcn_mfma_f32_16x16x32_bf16(fA[1][kt], bfr[nt][kt], acc[1][nt],0,0,0);
    }
  }
  if (wid >= 4){
#pragma unroll
    for (int mt=0; mt<2; ++mt)
#pragma unroll
      for (int nt=0; nt<6; ++nt){
        int n = nt*16 + l15, row = mt*16 + q*4;
        *(float4v*)(red + ((wid-4)*96 + n)*RS2 + row) = acc[mt][nt];
      }
  }
  __syncthreads();
  if (wid < 4){
#pragma unroll
    for (int mt=0; mt<2; ++mt)
#pragma unroll
      for (int nt=0; nt<6; ++nt){
        int n = nt*16 + l15, row = mt*16 + q*4;
        float4v* p = (float4v*)(red + (wid*96 + n)*RS2 + row);
        float4v v = *p;
        *p = v + acc[mt][nt];
      }
  }
  __syncthreads();
}

__global__ __launch_bounds__(NTHR, 2) void mgru_fused(
    const int*   __restrict__ x,    const float* __restrict__ h0,
    const float* __restrict__ emb,
    const float* __restrict__ Wih0, const float* __restrict__ Whh0,
    const float* __restrict__ bih0, const float* __restrict__ bhh0,
    const float* __restrict__ Wih1, const float* __restrict__ Whh1,
    const float* __restrict__ bih1, const float* __restrict__ bhh1,
    const float* __restrict__ gamma, const float* __restrict__ beta,
    const float* __restrict__ Wout, const float* __restrict__ bout,
    float* __restrict__ out, char* ws)
{
  __shared__ __align__(16) char smem[LDS_BYTES];
  float* red = (float*)smem;

  unsigned* f0  = (unsigned*)(ws + OFF_F0);
  unsigned* f1  = (unsigned*)(ws + OFF_F1);
  unsigned* f2  = (unsigned*)(ws + OFF_F2);
  unsigned* fin = (unsigned*)(ws + OFF_FIN);
  unsigned short* y0b   = (unsigned short*)(ws + M_OFF_Y0);
  unsigned short* y1    = (unsigned short*)(ws + M_OFF_Y1);
  unsigned short* h1i   = (unsigned short*)(ws + M_OFF_H1I);
  float*          T0    = (float*)(ws + M_OFF_T0);
  float*          stats = (float*)(ws + M_OFF_ST);     // [2 bg][2][1024]
  float*          xgring= (float*)(ws + M_OFF_XG);

  const int tid  = threadIdx.x;
  const int lane = tid & 63;
  const int wid  = tid >> 6;
  const int wg   = blockIdx.x;
  const int l15 = lane & 15, q = lane >> 4;
  float dummy = (float)tid * 1e-30f + 1.0f;

  if (wg >= NWRK){
    // heater: keep clocks boosted; then join epilogue
    for(;;){
      for (int i=0;i<64;++i) burn(dummy);
      unsigned v = __hip_atomic_load(fin, __ATOMIC_RELAXED, __HIP_MEMORY_SCOPE_AGENT);
      if (v >= (unsigned)NWRK) break;
    }
    if (tid == 0) __threadfence();          // acquire
    __syncthreads();
    if (dummy == 1234.5678f) ((volatile float*)smem)[0] = dummy;
    goto epilogue;
  }

  {
    // one-time acquire
    if (tid == 0) __threadfence();
    __syncthreads();

    const int role = (wg < 64) ? 0 : (wg < 128 ? 1 : 2);

    if (role == 0){
      // ====== layer-0 chain, 2D: WG(bg,cg) owns 32 batches x 32 ch ======
      const int rw = wg, bg = rw >> 5, cg = rw & 31;
      const int b0 = bg*32, ch0 = cg*32;
      const int fidx = bg*32 + cg;
      const int g = tid;                 // gate thread id (tid<128)
      const int b = b0 + (g & 31);
      const int oct = g >> 5;            // 0..3 -> 8-channel octet
      short8 bfr0[6][4];
      float hprev[8] = {0,0,0,0,0,0,0,0};
      float br[8], bz[8], bn[8];

      if (tid < 128){
        short8 pk;
#pragma unroll
        for (int j=0;j<8;++j){
          int ch = ch0 + oct*8 + j;
          hprev[j] = h0[(size_t)b*NHID + ch];
          br[j] = bhh0[ch]; bz[j] = bhh0[NHID + ch]; bn[j] = bhh0[2*NHID + ch];
          pk[j] = (short)f2bf(hprev[j]);
        }
        stc16(y0b + (size_t)b*NHID + ch0 + oct*8, pk);   // slot0 = y0(-1)
        drain_vm();
      }
      __syncthreads();
      if (tid == 0) setflag(f0 + (size_t)fidx*16, 1u);

      // T0 slice: this WG's 96 gate-channels (idempotent across bg dup)
      for (int e = tid; e < NVOC*96; e += NTHR){
        int v = e / 96, n = e - v*96;
        int gate = n >> 5, c32 = n & 31;
        int grow = gate*NHID + ch0 + c32;
        const float4v* e4 = (const float4v*)(emb  + (size_t)v*NHID);
        const float4v* w4 = (const float4v*)(Wih0 + (size_t)grow*NHID);
        float acc = 0.f;
        for (int k=0;k<NHID/4;++k){
          float4v a = e4[k], bb = w4[k];
          acc += a[0]*bb[0] + a[1]*bb[1] + a[2]*bb[2] + a[3]*bb[3];
        }
        T0[(size_t)v*3*NHID + grow] = acc + bih0[grow];
      }
      load_bfrags6(Whh0, ch0, bfr0, lane, wid);
      __syncthreads();

      for (int t = 0; t < NSEQ; ++t){
        waitflags32(f0, bg*32, t+1, lane, dummy);   // own group: y0(t-1) rows ready
        short8 fA[2][4];
        load_a2(y0b + (size_t)t*SL, b0, fA, lane, wid);
        gemm2d(fA, bfr0, red, lane, wid);
        if (tid < 128){
          int tok = x[(size_t)b*NSEQ + t];
          const float* tp = T0 + (size_t)tok*3*NHID;
          int m = g & 31;
          short8 pk;
#pragma unroll
          for (int j=0;j<8;++j){
            int c32 = oct*8 + j, ch = ch0 + c32;
            float hr = br[j], hz = bz[j], hn = bn[j];
#pragma unroll
            for (int w=0;w<4;++w){
              hr += red[(w*96 +      c32)*RS2 + m];
              hz += red[(w*96 + 32 + c32)*RS2 + m];
              hn += red[(w*96 + 64 + c32)*RS2 + m];
            }
            float r = sigm(tp[ch] + hr);
            float z = sigm(tp[NHID + ch] + hz);
            float n = tanh_f(tp[2*NHID + ch] + r*hn);
            float hnv = (1.f - z)*n + z*hprev[j];
            hprev[j] = hnv;
            pk[j] = (short)f2bf(hnv);
          }
          stc16(y0b + (size_t)(t+1)*SL + (size_t)b*NHID + ch0 + oct*8, pk);
          drain_vm();
        }
        __syncthreads();
        if (tid == 0) setflag(f0 + (size_t)fidx*16, (unsigned)(t+2));
      }

    } else if (role == 1){
      // ====== xg producer (off-chain): xg(t) = Wih1 x y0(t) + bih1 ======
      const int sub = wg - 64, ch0 = sub*16;
      int rowbase[3] = {ch0, NHID + ch0, 2*NHID + ch0};
      short8 wf[3][4];
      load_bfrags(Wih1, rowbase, wf, lane, wid);
      __syncthreads();

      for (int t = 0; t < NSEQ; ++t){
        if ((t & 3) == 0 && t >= 16)
          waitflags_slow64(f2, t-11, lane, dummy);    // ring WAR guard vs role2
        waitflags64(f0, t+2, lane, dummy);            // y0(t) full slab ready
        short8 fB[4][4];
        load_a16_plain(y0b + (size_t)(t+1)*SL + (size_t)l15*NHID + wid*128 + q*8, fB);
        gemm_frags(fB, wf, red, lane, wid);
        // publish: bias-first then w=0..3 (bit-exact with baseline x-side)
        float* xgw = xgring + ((size_t)(t & (XG_SLOTS-1))*64 + (size_t)sub)*3072;
#pragma unroll
        for (int i=0;i<6;++i){
          int idx = tid + i*512;           // 0..3071
          int n = idx >> 6, row = idx & 63;
          float v = bih1[(n>>4)*NHID + ch0 + (n&15)];
          v += red[(      n)*RS + row];
          v += red[( 48 + n)*RS + row];
          v += red[( 96 + n)*RS + row];
          v += red[(144 + n)*RS + row];
          stc4(xgw + idx, v);
        }
        drain_vm();
        __syncthreads();                   // publish reads of red done; WAR safe
        if (tid == 0) setflag(f1 + (size_t)sub*16, (unsigned)(t+2));
      }

    } else {
      // ====== layer-1 chain, 2D: single gemm on the critical path ======
      const int rw = wg - 128, bg = rw >> 5, cg = rw & 31;
      const int b0 = bg*32, ch0 = cg*32;
      const int fidx = bg*32 + cg;
      const int g = tid;
      const int b = b0 + (g & 31);
      const int oct = g >> 5;
      short8 bfrH[6][4];
      float hprev[8] = {0,0,0,0,0,0,0,0};
      float bhr[8], bhz[8], bhn[8];
      float s1[8] = {0,0,0,0,0,0,0,0}, s2[8] = {0,0,0,0,0,0,0,0};

      if (tid < 128){
        short8 pk;
#pragma unroll
        for (int j=0;j<8;++j){
          int ch = ch0 + oct*8 + j;
          hprev[j] = h0[(size_t)NB*NHID + (size_t)b*NHID + ch];
          bhr[j] = bhh1[ch]; bhz[j] = bhh1[NHID + ch]; bhn[j] = bhh1[2*NHID + ch];
          pk[j] = (short)f2bf(hprev[j]);
        }
        stc16(h1i + (size_t)b*NHID + ch0 + oct*8, pk);
        drain_vm();
      }
      __syncthreads();
      if (tid == 0) setflag(f2 + (size_t)fidx*16, 1u);

      load_bfrags6(Whh1, ch0, bfrH, lane, wid);
      __syncthreads();

      for (int t = 0; t < NSEQ; ++t){
        waitflags32(f2, bg*32, t+1, lane, dummy);   // own group: y1(t-1) rows ready
        const unsigned short* hsrc = (t == 0) ? h1i : (y1 + (size_t)(t-1)*SL);
        short8 fH[2][4];
        load_a2(hsrc, b0, fH, lane, wid);
        gemm2d(fH, bfrH, red, lane, wid);
        float hrv[8], hzv[8], hnv_[8];
        if (tid < 128){
          int m = g & 31;
#pragma unroll
          for (int j=0;j<8;++j){
            int c32 = oct*8 + j;
            float hr = bhr[j], hz = bhz[j], hn = bhn[j];
#pragma unroll
            for (int w=0;w<4;++w){
              hr += red[(w*96 +      c32)*RS2 + m];
              hz += red[(w*96 + 32 + c32)*RS2 + m];
              hn += red[(w*96 + 64 + c32)*RS2 + m];
            }
            hrv[j] = hr; hzv[j] = hz; hnv_[j] = hn;
          }
        }
        waitflags2(f1, cg*2, t+2, lane, dummy);     // xg(t) for our 2 ch-16 subs
        if (tid < 128){
          const float* xgp = xgring + (size_t)(t & (XG_SLOTS-1))*64*3072;
          short8 pk;
#pragma unroll
          for (int j=0;j<8;++j){
            int ch = ch0 + oct*8 + j;
            int sub1 = ch >> 4, c16 = ch & 15;
            const float* q0 = xgp + (size_t)sub1*3072 + (size_t)c16*64 + b;
            float xr = __hip_atomic_load(q0,           __ATOMIC_RELAXED, __HIP_MEMORY_SCOPE_AGENT);
            float xz = __hip_atomic_load(q0 + 16*64,   __ATOMIC_RELAXED, __HIP_MEMORY_SCOPE_AGENT);
            float xn = __hip_atomic_load(q0 + 32*64,   __ATOMIC_RELAXED, __HIP_MEMORY_SCOPE_AGENT);
            float r  = sigm(xr + hrv[j]);
            float z  = sigm(xz + hzv[j]);
            float nn = tanh_f(xn + r*hnv_[j]);
            float hnew = (1.f - z)*nn + z*hprev[j];
            hprev[j] = hnew;
            unsigned short hb = f2bf(hnew);
            pk[j] = (short)hb;
            float hq = bf2f(hb);
            s1[j] += hq; s2[j] += hq*hq;
          }
          stc16(y1 + (size_t)t*SL + (size_t)b*NHID + ch0 + oct*8, pk);
          drain_vm();
        }
        __syncthreads();
        if (tid == 0) setflag(f2 + (size_t)fidx*16, (unsigned)(t+2));
      }

      // BN stats: per-channel sums over this WG's 32 batches (ascending i),
      // cross-bg summed ascending in epilogue -> bit-identical fold order.
      {
        float* sb = (float*)smem;
        __syncthreads();
        if (tid < 128){
#pragma unroll
          for (int j=0;j<8;++j) sb[(oct*8 + j)*32 + (g & 31)] = s1[j];
        }
        __syncthreads();
        if (tid < 32){
          float a = 0.f;
          for (int i=0;i<32;++i) a += sb[tid*32 + i];
          stats[(size_t)bg*2048 + ch0 + tid] = a;
        }
        __syncthreads();
        if (tid < 128){
#pragma unroll
          for (int j=0;j<8;++j) sb[(oct*8 + j)*32 + (g & 31)] = s2[j];
        }
        __syncthreads();
        if (tid < 32){
          float a = 0.f;
          for (int i=0;i<32;++i) a += sb[tid*32 + i];
          stats[(size_t)bg*2048 + 1024 + ch0 + tid] = a;
        }
      }
    }

    // ======== fin barrier with ONE wbL2/inv fence pair per WG ========
    __syncthreads();
    if (tid == 0){
      __threadfence();          // release (y1 sc1 + stats plain -> L2 wb)
      sig(fin);
      waitc(fin, NWRK, dummy);
      __threadfence();          // acquire
    }
    __syncthreads();
    if (dummy == 1234.5678f) ((volatile float*)smem)[0] = dummy;
  }

epilogue:
  // ============ epilogue: fold BN into Wout, GEMM -> out ============
  {
    const float inv_n = 1.f/32768.f;

    float* bpart    = (float*)smem;
    float* bprime_l = (float*)(smem + 2048);
    {
      int v = tid >> 4, k0 = tid & 15;
      float partial = 0.f;
      if (v < NVOC){
        for (int k = k0; k < NHID; k += 16){
          float s1k = stats[k] + stats[2048 + k];
          float s2k = stats[1024 + k] + stats[3072 + k];
          float mu  = s1k*inv_n;
          float var = s2k*inv_n - mu*mu;
          float sc  = gamma[k]*rsqrtf(var + EPSV);
          partial += (beta[k] - mu*sc) * Wout[(size_t)v*NHID + k];
        }
      }
      bpart[tid] = partial;
    }
    __syncthreads();
    if (tid < 32){
      float bpv = 0.f;
      for (int j=0;j<16;++j) bpv += bpart[tid*16 + j];
      bprime_l[tid] = (tid < NVOC) ? (bpv + bout[tid]) : 0.f;
    }
    __syncthreads();
    float bp_a = bprime_l[l15];
    float bp_b = (l15 < 15) ? bprime_l[16 + l15] : 0.f;
    __syncthreads();

    unsigned short* wsc = (unsigned short*)smem;   // [31][1032] bf16
    for (int e = tid; e < NVOC*1032; e += NTHR){
      int v = e / 1032, k = e - v*1032;
      float val = 0.f;
      if (k < NHID){
        float s1k = stats[k] + stats[2048 + k];
        float s2k = stats[1024 + k] + stats[3072 + k];
        float mu  = s1k*inv_n;
        float var = s2k*inv_n - mu*mu;
        float sc  = gamma[k]*rsqrtf(var + EPSV);
        val = Wout[(size_t)v*NHID + k] * sc;
      }
      wsc[e] = f2bf(val);
    }
    __syncthreads();

    int wglob = wg*8 + wid;                 // 0..2047
    if ((wglob & 3) == 0){
      int J = wglob >> 2;                   // 0..511
      float4v acc[4][2];
#pragma unroll
      for (int mt=0;mt<4;++mt){ acc[mt][0] = (float4v){0,0,0,0}; acc[mt][1] = (float4v){0,0,0,0}; }
      const unsigned short* abase = y1 + (size_t)(J*64 + l15)*NHID + q*8;
      const short8 zero8 = (short8){0,0,0,0,0,0,0,0};
#pragma unroll 4
      for (int kt=0; kt<32; ++kt){
        short8 bv0 = *(const short8*)(wsc + (size_t)l15*1032 + kt*32 + q*8);
        short8 bv1 = (l15 < 15) ? *(const short8*)(wsc + (size_t)(16+l15)*1032 + kt*32 + q*8) : zero8;
        short8 a0 = *(const short8*)(abase + (size_t)kt*32);
        short8 a1 = *(const short8*)(abase + 16*NHID + (size_t)kt*32);
        short8 a2 = *(const short8*)(abase + 32*NHID + (size_t)kt*32);
        short8 a3 = *(const short8*)(abase + 48*NHID + (size_t)kt*32);
        acc[0][0] = __builtin_amdgcn_mfma_f32_16x16x32_bf16(a0, bv0, acc[0][0],0,0,0);
        acc[1][0] = __builtin_amdgcn_mfma_f32_16x16x32_bf16(a1, bv0, acc[1][0],0,0,0);
        acc[2][0] = __builtin_amdgcn_mfma_f32_16x16x32_bf16(a2, bv0, acc[2][0],0,0,0);
        acc[3][0] = __builtin_amdgcn_mfma_f32_16x16x32_bf16(a3, bv0, acc[3][0],0,0,0);
        acc[0][1] = __builtin_amdgcn_mfma_f32_16x16x32_bf16(a0, bv1, acc[0][1],0,0,0);
        acc[1][1] = __builtin_amdgcn_mfma_f32_16x16x32_bf16(a1, bv1, acc[1][1],0,0,0);
        acc[2][1] = __builtin_amdgcn_mfma_f32_16x16x32_bf16(a2, bv1, acc[2][1],0,0,0);
        acc[3][1] = __builtin_amdgcn_mfma_f32_16x16x32_bf16(a3, bv1, acc[3][1],0,0,0);
      }
#pragma unroll
      for (int mt=0;mt<4;++mt){
#pragma unroll
        for (int nt=0;nt<2;++nt){
          int v = nt*16 + l15;
          if (v < NVOC){
            float bpv = (nt==0) ? bp_a : bp_b;
            int r0 = J*64 + mt*16 + q*4;
#pragma unroll
            for (int i2=0;i2<4;++i2){
              int r = r0 + i2;
              int bb = r & 63, tt = r >> 6;
              out[(size_t)(bb*NSEQ + tt)*NVOC + v] = acc[mt][nt][i2] + bpv;
            }
          }
        }
      }
    }
  }
}

extern "C" void kernel_launch(void* const* d_in, const int* in_sizes, int n_in,
                              void* d_out, int out_size, void* d_ws, size_t ws_size,
                              hipStream_t stream) {
  (void)in_sizes; (void)n_in; (void)out_size; (void)ws_size;
  hipMemsetAsync(d_ws, 0, CNT_BYTES, stream);   // zero flags + fin counter
  mgru_fused<<<dim3(NGRID), dim3(NTHR), 0, stream>>>(
      (const int*)d_in[0],  (const float*)d_in[1],  (const float*)d_in[2],
      (const float*)d_in[3], (const float*)d_in[4], (const float*)d_in[5],
      (const float*)d_in[6], (const float*)d_in[7], (const float*)d_in[8],
      (const float*)d_in[9], (const float*)d_in[10], (const float*)d_in[11],
      (const float*)d_in[12], (const float*)d_in[13], (const float*)d_in[14],
      (float*)d_out, (char*)d_ws);
}

// Round 8
// 4048.536 us; speedup vs baseline: 4.3949x; 1.0303x over previous
//
#include <hip/hip_runtime.h>
#include <cstddef>
#include <stdint.h>

// ---------------- problem constants ----------------
#define NHID 1024
#define NVOC 31
#define NB   64
#define NSEQ 512
#define NWRK 192     // 64 role0 (L0) + 64 role1 (xg) + 64 role2 (L1) — ALL 2D
#define NGRID 256    // + 64 heater WGs
#define NTHR 512     // 8 waves
#define EPSV 1e-5f
#define RS2  36      // 2D LDS reduce stride (384 rows x 36)
#define SL   (NB*NHID)   // one h-state slot (128KB bf16)
#define XG_SLOTS 16

typedef __attribute__((ext_vector_type(8))) short short8;   // 8 x bf16
typedef __attribute__((ext_vector_type(4))) float float4v;

// ---------------- sync area: 64B-strided flags (one line per WG) ----
#define OFF_F0  0               // 64 flags: role0 (idx bg*32+cg); f=t+2 <=> step t done
#define OFF_F1  4096            // 64 flags: role1 (idx bg*32+cg): xg tile published
#define OFF_F2  8192            // 64 flags: role2 (idx bg*32+cg)
#define OFF_FIN 12288
#define CNT_BYTES 12352

// ---------------- MONO layout: write-once addresses -> plain cached reads ok
#define M_OFF_Y0  12544                             // 513 slots: slot t+1 = y0(t)
#define M_OFF_Y1  (M_OFF_Y0 + 513ull*SL*2)          // 512 slots: y1(t)
#define M_OFF_H1I (M_OFF_Y1 + 512ull*SL*2)          // h1(-1)
#define M_OFF_T0  (M_OFF_H1I + (unsigned long long)SL*2)
#define M_OFF_ST  (M_OFF_T0 + 31ull*3*NHID*4)       // statsP[2 bg][2][1024] f32
// ring: 16 slots x 64 (bg,cg) tiles x 3072 f32; tile = [96 n][32 m]
#define M_OFF_XG  (M_OFF_ST + 16384ull)

// LDS: 2D red = 384*36*4 = 55296; epilogue wsc = 63984
#define LDS_BYTES 65024

__device__ __forceinline__ unsigned short f2bf(float f){
  unsigned u = __builtin_bit_cast(unsigned, f);
  u += 0x7fffu + ((u >> 16) & 1u);               // RNE
  return (unsigned short)(u >> 16);
}
__device__ __forceinline__ float bf2f(unsigned short h){
  unsigned u = ((unsigned)h) << 16;
  return __builtin_bit_cast(float, u);
}
__device__ __forceinline__ float sigm(float x){ return 1.f/(1.f + __expf(-x)); }
__device__ __forceinline__ float tanh_f(float x){ return 1.f - 2.f/(__expf(2.f*x) + 1.f); }

__device__ __forceinline__ void burn(float& d){
#pragma unroll
  for (int i=0;i<16;++i)
    asm volatile("v_fmac_f32 %0, %1, %2" : "+v"(d) : "v"(d), "v"(d));
}

// ---- flag sync ----
__device__ __forceinline__ void setflag(unsigned* f, unsigned v){
  __hip_atomic_store(f, v, __ATOMIC_RELAXED, __HIP_MEMORY_SCOPE_AGENT);
}
__device__ __forceinline__ void waitflags32(const unsigned* f, int base32, int target, int lane, float& d){
  const unsigned* p = f + (size_t)(base32 + (lane & 31))*16;
  for(;;){
    int v = (int)__hip_atomic_load(p, __ATOMIC_RELAXED, __HIP_MEMORY_SCOPE_AGENT);
    if (__all(v >= target)) break;
    burn(d);
  }
  asm volatile("" ::: "memory");
}
__device__ __forceinline__ void waitflag1(const unsigned* f, int idx, int target, float& d){
  const unsigned* p = f + (size_t)idx*16;
  while ((int)__hip_atomic_load(p, __ATOMIC_RELAXED, __HIP_MEMORY_SCOPE_AGENT) < target)
    burn(d);
  asm volatile("" ::: "memory");
}
__device__ __forceinline__ void waitflag1_slow(const unsigned* f, int idx, int target, float& d){
  const unsigned* p = f + (size_t)idx*16;
  while ((int)__hip_atomic_load(p, __ATOMIC_RELAXED, __HIP_MEMORY_SCOPE_AGENT) < target){
    burn(d); burn(d); burn(d); burn(d);
  }
  asm volatile("" ::: "memory");
}
__device__ __forceinline__ void sig(unsigned* c){
  __hip_atomic_fetch_add(c, 1u, __ATOMIC_RELAXED, __HIP_MEMORY_SCOPE_AGENT);
}
__device__ __forceinline__ void waitc(unsigned* c, unsigned v, float& d){
  while (__hip_atomic_load(c, __ATOMIC_RELAXED, __HIP_MEMORY_SCOPE_AGENT) < v)
    burn(d);
}

// sc1: write past the non-coherent per-XCD L2 (R4 proved sc0 breaks)
__device__ __forceinline__ void stc16(void* p, short8 v){
  asm volatile("global_store_dwordx4 %0, %1, off sc1"
               :: "v"((unsigned long long)(uintptr_t)p), "v"(v) : "memory");
}
__device__ __forceinline__ void stc4(void* p, float v){
  asm volatile("global_store_dword %0, %1, off sc1"
               :: "v"((unsigned long long)(uintptr_t)p), "v"(v) : "memory");
}
__device__ __forceinline__ void drain_vm(){
  asm volatile("s_waitcnt vmcnt(0)" ::: "memory");
}

// ---- 2D machinery (all roles): WG owns 32 batches x 32 channels ----
// weight B-frags: 6 n-tiles; n-index in red = gate*32 + c32
__device__ __forceinline__ void load_bfrags6(const float* W, int ch0,
                                             short8 (&bfr)[6][4], int lane, int wid)
{
  const int l15 = lane & 15, q = lane >> 4;
#pragma unroll
  for (int nt=0; nt<6; ++nt){
    int grow = (nt>>1)*NHID + ch0 + (nt&1)*16 + l15;
    const float* wp0 = W + (size_t)grow*NHID + wid*128 + q*8;
#pragma unroll
    for (int kt=0; kt<4; ++kt){
      const float* wp = wp0 + kt*32;
      short8 fr;
#pragma unroll
      for (int j=0;j<8;++j) fr[j] = (short)f2bf(wp[j]);
      bfr[nt][kt] = fr;
    }
  }
}
__device__ __forceinline__ void load_a2(const unsigned short* slab, int b0,
                                        short8 (&f)[2][4], int lane, int wid)
{
#pragma unroll
  for (int mt=0;mt<2;++mt){
    const short8* p = (const short8*)(slab + (size_t)(b0 + mt*16 + (lane&15))*NHID
                                      + wid*128 + (lane>>4)*8);
#pragma unroll
    for (int kt=0;kt<4;++kt) f[mt][kt] = p[kt*4];
  }
}
// M=32,N=96,K=1024: 8 waves split K 8-way (wid*128); pair-reduce (w, w+4)
__device__ __forceinline__ void gemm2d(const short8 (&fA)[2][4],
                                       const short8 (&bfr)[6][4],
                                       float* red, int lane, int wid)
{
  const int l15 = lane & 15, q = lane >> 4;
  float4v acc[2][6];
#pragma unroll
  for (int mt=0; mt<2; ++mt)
#pragma unroll
    for (int nt=0; nt<6; ++nt) acc[mt][nt] = (float4v){0.f,0.f,0.f,0.f};
#pragma unroll
  for (int kt=0; kt<4; ++kt){
#pragma unroll
    for (int nt=0; nt<6; ++nt){
      acc[0][nt] = __builtin_amdgcn_mfma_f32_16x16x32_bf16(fA[0][kt], bfr[nt][kt], acc[0][nt],0,0,0);
      acc[1][nt] = __builtin_amdgcn_mfma_f32_16x16x32_bf16(fA[1][kt], bfr[nt][kt], acc[1][nt],0,0,0);
    }
  }
  if (wid >= 4){
#pragma unroll
    for (int mt=0; mt<2; ++mt)
#pragma unroll
      for (int nt=0; nt<6; ++nt){
        int n = nt*16 + l15, row = mt*16 + q*4;
        *(float4v*)(red + ((wid-4)*96 + n)*RS2 + row) = acc[mt][nt];
      }
  }
  __syncthreads();
  if (wid < 4){
#pragma unroll
    for (int mt=0; mt<2; ++mt)
#pragma unroll
      for (int nt=0; nt<6; ++nt){
        int n = nt*16 + l15, row = mt*16 + q*4;
        float4v* p = (float4v*)(red + (wid*96 + n)*RS2 + row);
        float4v v = *p;
        *p = v + acc[mt][nt];
      }
  }
  __syncthreads();
}

__global__ __launch_bounds__(NTHR, 2) void mgru_fused(
    const int*   __restrict__ x,    const float* __restrict__ h0,
    const float* __restrict__ emb,
    const float* __restrict__ Wih0, const float* __restrict__ Whh0,
    const float* __restrict__ bih0, const float* __restrict__ bhh0,
    const float* __restrict__ Wih1, const float* __restrict__ Whh1,
    const float* __restrict__ bih1, const float* __restrict__ bhh1,
    const float* __restrict__ gamma, const float* __restrict__ beta,
    const float* __restrict__ Wout, const float* __restrict__ bout,
    float* __restrict__ out, char* ws)
{
  __shared__ __align__(16) char smem[LDS_BYTES];
  float* red = (float*)smem;

  unsigned* f0  = (unsigned*)(ws + OFF_F0);
  unsigned* f1  = (unsigned*)(ws + OFF_F1);
  unsigned* f2  = (unsigned*)(ws + OFF_F2);
  unsigned* fin = (unsigned*)(ws + OFF_FIN);
  unsigned short* y0b   = (unsigned short*)(ws + M_OFF_Y0);
  unsigned short* y1    = (unsigned short*)(ws + M_OFF_Y1);
  unsigned short* h1i   = (unsigned short*)(ws + M_OFF_H1I);
  float*          T0    = (float*)(ws + M_OFF_T0);
  float*          stats = (float*)(ws + M_OFF_ST);     // [2 bg][2][1024]
  float*          xgring= (float*)(ws + M_OFF_XG);

  const int tid  = threadIdx.x;
  const int lane = tid & 63;
  const int wid  = tid >> 6;
  const int wg   = blockIdx.x;
  const int l15 = lane & 15, q = lane >> 4;
  float dummy = (float)tid * 1e-30f + 1.0f;

  if (wg >= NWRK){
    // heater: keep clocks boosted; then join epilogue
    for(;;){
      for (int i=0;i<64;++i) burn(dummy);
      unsigned v = __hip_atomic_load(fin, __ATOMIC_RELAXED, __HIP_MEMORY_SCOPE_AGENT);
      if (v >= (unsigned)NWRK) break;
    }
    if (tid == 0) __threadfence();          // acquire
    __syncthreads();
    if (dummy == 1234.5678f) ((volatile float*)smem)[0] = dummy;
    goto epilogue;
  }

  {
    // one-time acquire
    if (tid == 0) __threadfence();
    __syncthreads();

    const int role = (wg < 64) ? 0 : (wg < 128 ? 1 : 2);

    if (role == 0){
      // ====== layer-0 chain, 2D: WG(bg,cg) owns 32 batches x 32 ch ======
      const int rw = wg, bg = rw >> 5, cg = rw & 31;
      const int b0 = bg*32, ch0 = cg*32;
      const int fidx = bg*32 + cg;
      const int g = tid;                 // gate thread id (tid<128)
      const int b = b0 + (g & 31);
      const int oct = g >> 5;            // 0..3 -> 8-channel octet
      short8 bfr0[6][4];
      float hprev[8] = {0,0,0,0,0,0,0,0};
      float br[8], bz[8], bn[8];

      if (tid < 128){
        short8 pk;
#pragma unroll
        for (int j=0;j<8;++j){
          int ch = ch0 + oct*8 + j;
          hprev[j] = h0[(size_t)b*NHID + ch];
          br[j] = bhh0[ch]; bz[j] = bhh0[NHID + ch]; bn[j] = bhh0[2*NHID + ch];
          pk[j] = (short)f2bf(hprev[j]);
        }
        stc16(y0b + (size_t)b*NHID + ch0 + oct*8, pk);   // slot0 = y0(-1)
        drain_vm();
      }
      __syncthreads();
      if (tid == 0) setflag(f0 + (size_t)fidx*16, 1u);

      // T0 slice: this WG's 96 gate-channels (idempotent across bg dup)
      for (int e = tid; e < NVOC*96; e += NTHR){
        int v = e / 96, n = e - v*96;
        int gate = n >> 5, c32 = n & 31;
        int grow = gate*NHID + ch0 + c32;
        const float4v* e4 = (const float4v*)(emb  + (size_t)v*NHID);
        const float4v* w4 = (const float4v*)(Wih0 + (size_t)grow*NHID);
        float acc = 0.f;
        for (int k=0;k<NHID/4;++k){
          float4v a = e4[k], bb = w4[k];
          acc += a[0]*bb[0] + a[1]*bb[1] + a[2]*bb[2] + a[3]*bb[3];
        }
        T0[(size_t)v*3*NHID + grow] = acc + bih0[grow];
      }
      load_bfrags6(Whh0, ch0, bfr0, lane, wid);
      __syncthreads();

      for (int t = 0; t < NSEQ; ++t){
        waitflags32(f0, bg*32, t+1, lane, dummy);   // own group: y0(t-1) rows ready
        short8 fA[2][4];
        load_a2(y0b + (size_t)t*SL, b0, fA, lane, wid);
        gemm2d(fA, bfr0, red, lane, wid);
        if (tid < 128){
          int tok = x[(size_t)b*NSEQ + t];
          const float* tp = T0 + (size_t)tok*3*NHID;
          int m = g & 31;
          short8 pk;
#pragma unroll
          for (int j=0;j<8;++j){
            int c32 = oct*8 + j, ch = ch0 + c32;
            float hr = br[j], hz = bz[j], hn = bn[j];
#pragma unroll
            for (int w=0;w<4;++w){
              hr += red[(w*96 +      c32)*RS2 + m];
              hz += red[(w*96 + 32 + c32)*RS2 + m];
              hn += red[(w*96 + 64 + c32)*RS2 + m];
            }
            float r = sigm(tp[ch] + hr);
            float z = sigm(tp[NHID + ch] + hz);
            float n = tanh_f(tp[2*NHID + ch] + r*hn);
            float hnv = (1.f - z)*n + z*hprev[j];
            hprev[j] = hnv;
            pk[j] = (short)f2bf(hnv);
          }
          stc16(y0b + (size_t)(t+1)*SL + (size_t)b*NHID + ch0 + oct*8, pk);
          drain_vm();
        }
        __syncthreads();
        if (tid == 0) setflag(f0 + (size_t)fidx*16, (unsigned)(t+2));
      }

    } else if (role == 1){
      // ====== xg producer, NOW 2D (R8): WG(bg,cg) computes the exact tile
      // its role2 counterpart consumes. Fan-in 64->32 (own bg's f0 flags),
      // slab read 128->64KB, role2's f1 wait -> single flag. Same K-split
      // (wid*128), pair-reduce, bias-first, w=0..3 -> bit-exact xg values.
      const int rw = wg - 64, bg = rw >> 5, cg = rw & 31;
      const int b0 = bg*32, ch0 = cg*32;
      const int fidx = bg*32 + cg;
      short8 wf[6][4];
      load_bfrags6(Wih1, ch0, wf, lane, wid);
      __syncthreads();

      for (int t = 0; t < NSEQ; ++t){
        if ((t & 3) == 0 && t >= 16)
          waitflag1_slow(f2, fidx, t-11, dummy);    // ring WAR guard vs counterpart
        waitflags32(f0, bg*32, t+2, lane, dummy);   // y0(t) rows b0..b0+31 ready
        short8 fB[2][4];
        load_a2(y0b + (size_t)(t+1)*SL, b0, fB, lane, wid);
        gemm2d(fB, wf, red, lane, wid);
        // publish tile [96 n][32 m]: bias-first then w=0..3 (bit-exact)
        float* xgw = xgring + ((size_t)(t & (XG_SLOTS-1))*64 + (size_t)fidx)*3072;
#pragma unroll
        for (int i=0;i<6;++i){
          int idx = tid + i*512;           // 0..3071 = n*32 + m
          int n = idx >> 5, m = idx & 31;
          float v = bih1[(n>>5)*NHID + ch0 + (n&31)];
          v += red[(      n)*RS2 + m];
          v += red[( 96 + n)*RS2 + m];
          v += red[(192 + n)*RS2 + m];
          v += red[(288 + n)*RS2 + m];
          stc4(xgw + idx, v);
        }
        drain_vm();
        __syncthreads();                   // red reads done; WAR safe for next gemm
        if (tid == 0) setflag(f1 + (size_t)fidx*16, (unsigned)(t+2));
      }

    } else {
      // ====== layer-1 chain, 2D: single gemm on the critical path ======
      const int rw = wg - 128, bg = rw >> 5, cg = rw & 31;
      const int b0 = bg*32, ch0 = cg*32;
      const int fidx = bg*32 + cg;
      const int g = tid;
      const int b = b0 + (g & 31);
      const int oct = g >> 5;
      short8 bfrH[6][4];
      float hprev[8] = {0,0,0,0,0,0,0,0};
      float bhr[8], bhz[8], bhn[8];
      float s1[8] = {0,0,0,0,0,0,0,0}, s2[8] = {0,0,0,0,0,0,0,0};

      if (tid < 128){
        short8 pk;
#pragma unroll
        for (int j=0;j<8;++j){
          int ch = ch0 + oct*8 + j;
          hprev[j] = h0[(size_t)NB*NHID + (size_t)b*NHID + ch];
          bhr[j] = bhh1[ch]; bhz[j] = bhh1[NHID + ch]; bhn[j] = bhh1[2*NHID + ch];
          pk[j] = (short)f2bf(hprev[j]);
        }
        stc16(h1i + (size_t)b*NHID + ch0 + oct*8, pk);
        drain_vm();
      }
      __syncthreads();
      if (tid == 0) setflag(f2 + (size_t)fidx*16, 1u);

      load_bfrags6(Whh1, ch0, bfrH, lane, wid);
      __syncthreads();

      for (int t = 0; t < NSEQ; ++t){
        waitflags32(f2, bg*32, t+1, lane, dummy);   // own group: y1(t-1) rows ready
        const unsigned short* hsrc = (t == 0) ? h1i : (y1 + (size_t)(t-1)*SL);
        short8 fH[2][4];
        load_a2(hsrc, b0, fH, lane, wid);
        gemm2d(fH, bfrH, red, lane, wid);
        float hrv[8], hzv[8], hnv_[8];
        if (tid < 128){
          int m = g & 31;
#pragma unroll
          for (int j=0;j<8;++j){
            int c32 = oct*8 + j;
            float hr = bhr[j], hz = bhz[j], hn = bhn[j];
#pragma unroll
            for (int w=0;w<4;++w){
              hr += red[(w*96 +      c32)*RS2 + m];
              hz += red[(w*96 + 32 + c32)*RS2 + m];
              hn += red[(w*96 + 64 + c32)*RS2 + m];
            }
            hrv[j] = hr; hzv[j] = hz; hnv_[j] = hn;
          }
        }
        waitflag1(f1, fidx, t+2, dummy);            // xg(t) tile from counterpart
        if (tid < 128){
          const float* xgt = xgring + ((size_t)(t & (XG_SLOTS-1))*64 + (size_t)fidx)*3072;
          int m = g & 31;
          short8 pk;
#pragma unroll
          for (int j=0;j<8;++j){
            int c32 = oct*8 + j;
            float xr = __hip_atomic_load(xgt + (size_t)(     c32)*32 + m, __ATOMIC_RELAXED, __HIP_MEMORY_SCOPE_AGENT);
            float xz = __hip_atomic_load(xgt + (size_t)(32 + c32)*32 + m, __ATOMIC_RELAXED, __HIP_MEMORY_SCOPE_AGENT);
            float xn = __hip_atomic_load(xgt + (size_t)(64 + c32)*32 + m, __ATOMIC_RELAXED, __HIP_MEMORY_SCOPE_AGENT);
            float r  = sigm(xr + hrv[j]);
            float z  = sigm(xz + hzv[j]);
            float nn = tanh_f(xn + r*hnv_[j]);
            float hnew = (1.f - z)*nn + z*hprev[j];
            hprev[j] = hnew;
            unsigned short hb = f2bf(hnew);
            pk[j] = (short)hb;
            float hq = bf2f(hb);
            s1[j] += hq; s2[j] += hq*hq;
          }
          stc16(y1 + (size_t)t*SL + (size_t)b*NHID + ch0 + oct*8, pk);
          drain_vm();
        }
        __syncthreads();
        if (tid == 0) setflag(f2 + (size_t)fidx*16, (unsigned)(t+2));
      }

      // BN stats: per-channel sums over this WG's 32 batches (ascending i),
      // cross-bg summed ascending in epilogue -> bit-identical fold order.
      {
        float* sb = (float*)smem;
        __syncthreads();
        if (tid < 128){
#pragma unroll
          for (int j=0;j<8;++j) sb[(oct*8 + j)*32 + (g & 31)] = s1[j];
        }
        __syncthreads();
        if (tid < 32){
          float a = 0.f;
          for (int i=0;i<32;++i) a += sb[tid*32 + i];
          stats[(size_t)bg*2048 + ch0 + tid] = a;
        }
        __syncthreads();
        if (tid < 128){
#pragma unroll
          for (int j=0;j<8;++j) sb[(oct*8 + j)*32 + (g & 31)] = s2[j];
        }
        __syncthreads();
        if (tid < 32){
          float a = 0.f;
          for (int i=0;i<32;++i) a += sb[tid*32 + i];
          stats[(size_t)bg*2048 + 1024 + ch0 + tid] = a;
        }
      }
    }

    // ======== fin barrier with ONE wbL2/inv fence pair per WG ========
    __syncthreads();
    if (tid == 0){
      __threadfence();          // release (y1 sc1 + stats plain -> L2 wb)
      sig(fin);
      waitc(fin, NWRK, dummy);
      __threadfence();          // acquire
    }
    __syncthreads();
    if (dummy == 1234.5678f) ((volatile float*)smem)[0] = dummy;
  }

epilogue:
  // ============ epilogue: fold BN into Wout, GEMM -> out ============
  {
    const float inv_n = 1.f/32768.f;

    float* bpart    = (float*)smem;
    float* bprime_l = (float*)(smem + 2048);
    {
      int v = tid >> 4, k0 = tid & 15;
      float partial = 0.f;
      if (v < NVOC){
        for (int k = k0; k < NHID; k += 16){
          float s1k = stats[k] + stats[2048 + k];
          float s2k = stats[1024 + k] + stats[3072 + k];
          float mu  = s1k*inv_n;
          float var = s2k*inv_n - mu*mu;
          float sc  = gamma[k]*rsqrtf(var + EPSV);
          partial += (beta[k] - mu*sc) * Wout[(size_t)v*NHID + k];
        }
      }
      bpart[tid] = partial;
    }
    __syncthreads();
    if (tid < 32){
      float bpv = 0.f;
      for (int j=0;j<16;++j) bpv += bpart[tid*16 + j];
      bprime_l[tid] = (tid < NVOC) ? (bpv + bout[tid]) : 0.f;
    }
    __syncthreads();
    float bp_a = bprime_l[l15];
    float bp_b = (l15 < 15) ? bprime_l[16 + l15] : 0.f;
    __syncthreads();

    unsigned short* wsc = (unsigned short*)smem;   // [31][1032] bf16
    for (int e = tid; e < NVOC*1032; e += NTHR){
      int v = e / 1032, k = e - v*1032;
      float val = 0.f;
      if (k < NHID){
        float s1k = stats[k] + stats[2048 + k];
        float s2k = stats[1024 + k] + stats[3072 + k];
        float mu  = s1k*inv_n;
        float var = s2k*inv_n - mu*mu;
        float sc  = gamma[k]*rsqrtf(var + EPSV);
        val = Wout[(size_t)v*NHID + k] * sc;
      }
      wsc[e] = f2bf(val);
    }
    __syncthreads();

    unsigned short* y1b = (unsigned short*)(ws + M_OFF_Y1);
    int wglob = wg*8 + wid;                 // 0..2047
    if ((wglob & 3) == 0){
      int J = wglob >> 2;                   // 0..511
      float4v acc[4][2];
#pragma unroll
      for (int mt=0;mt<4;++mt){ acc[mt][0] = (float4v){0,0,0,0}; acc[mt][1] = (float4v){0,0,0,0}; }
      const unsigned short* abase = y1b + (size_t)(J*64 + l15)*NHID + q*8;
      const short8 zero8 = (short8){0,0,0,0,0,0,0,0};
#pragma unroll 4
      for (int kt=0; kt<32; ++kt){
        short8 bv0 = *(const short8*)(wsc + (size_t)l15*1032 + kt*32 + q*8);
        short8 bv1 = (l15 < 15) ? *(const short8*)(wsc + (size_t)(16+l15)*1032 + kt*32 + q*8) : zero8;
        short8 a0 = *(const short8*)(abase + (size_t)kt*32);
        short8 a1 = *(const short8*)(abase + 16*NHID + (size_t)kt*32);
        short8 a2 = *(const short8*)(abase + 32*NHID + (size_t)kt*32);
        short8 a3 = *(const short8*)(abase + 48*NHID + (size_t)kt*32);
        acc[0][0] = __builtin_amdgcn_mfma_f32_16x16x32_bf16(a0, bv0, acc[0][0],0,0,0);
        acc[1][0] = __builtin_amdgcn_mfma_f32_16x16x32_bf16(a1, bv0, acc[1][0],0,0,0);
        acc[2][0] = __builtin_amdgcn_mfma_f32_16x16x32_bf16(a2, bv0, acc[2][0],0,0,0);
        acc[3][0] = __builtin_amdgcn_mfma_f32_16x16x32_bf16(a3, bv0, acc[3][0],0,0,0);
        acc[0][1] = __builtin_amdgcn_mfma_f32_16x16x32_bf16(a0, bv1, acc[0][1],0,0,0);
        acc[1][1] = __builtin_amdgcn_mfma_f32_16x16x32_bf16(a1, bv1, acc[1][1],0,0,0);
        acc[2][1] = __builtin_amdgcn_mfma_f32_16x16x32_bf16(a2, bv1, acc[2][1],0,0,0);
        acc[3][1] = __builtin_amdgcn_mfma_f32_16x16x32_bf16(a3, bv1, acc[3][1],0,0,0);
      }
#pragma unroll
      for (int mt=0;mt<4;++mt){
#pragma unroll
        for (int nt=0;nt<2;++nt){
          int v = nt*16 + l15;
          if (v < NVOC){
            float bpv = (nt==0) ? bp_a : bp_b;
            int r0 = J*64 + mt*16 + q*4;
#pragma unroll
            for (int i2=0;i2<4;++i2){
              int r = r0 + i2;
              int bb = r & 63, tt = r >> 6;
              out[(size_t)(bb*NSEQ + tt)*NVOC + v] = acc[mt][nt][i2] + bpv;
            }
          }
        }
      }
    }
  }
}

extern "C" void kernel_launch(void* const* d_in, const int* in_sizes, int n_in,
                              void* d_out, int out_size, void* d_ws, size_t ws_size,
                              hipStream_t stream) {
  (void)in_sizes; (void)n_in; (void)out_size; (void)ws_size;
  hipMemsetAsync(d_ws, 0, CNT_BYTES, stream);   // zero flags + fin counter
  mgru_fused<<<dim3(NGRID), dim3(NTHR), 0, stream>>>(
      (const int*)d_in[0],  (const float*)d_in[1],  (const float*)d_in[2],
      (const float*)d_in[3], (const float*)d_in[4], (const float*)d_in[5],
      (const float*)d_in[6], (const float*)d_in[7], (const float*)d_in[8],
      (const float*)d_in[9], (const float*)d_in[10], (const float*)d_in[11],
      (const float*)d_in[12], (const float*)d_in[13], (const float*)d_in[14],
      (float*)d_out, (char*)d_ws);
}

// Round 9
// 3911.741 us; speedup vs baseline: 4.5486x; 1.0350x over previous
//
#include <hip/hip_runtime.h>
#include <cstddef>
#include <stdint.h>

// ---------------- problem constants ----------------
#define NHID 1024
#define NVOC 31
#define NB   64
#define NSEQ 512
#define NWRK 192     // 64 role0 (L0) + 64 role1 (xg) + 64 role2 (L1) — ALL 2D
#define NGRID 256    // + 64 heater WGs
#define NTHR 512     // 8 waves
#define EPSV 1e-5f
#define RS2  36      // 2D LDS reduce stride (384 rows x 36)
#define SL   (NB*NHID)   // one h-state slot (128KB bf16)
#define XG_SLOTS 16

typedef __attribute__((ext_vector_type(8))) short short8;   // 8 x bf16
typedef __attribute__((ext_vector_type(4))) float float4v;

// ---------------- sync area: 64B-strided flags (one line per WG) ----
#define OFF_F0  0               // 64 flags: role0 (idx bg*32+cg); f=t+2 <=> step t done
#define OFF_F1  4096            // 64 flags: role1 (idx bg*32+cg): xg tile published
#define OFF_F2  8192            // 64 flags: role2 (idx bg*32+cg)
#define OFF_FIN 12288
#define CNT_BYTES 12352

// ---------------- MONO layout: write-once addresses -> plain cached reads ok
#define M_OFF_Y0  12544                             // 513 slots: slot t+1 = y0(t)
#define M_OFF_Y1  (M_OFF_Y0 + 513ull*SL*2)          // 512 slots: y1(t)
#define M_OFF_H1I (M_OFF_Y1 + 512ull*SL*2)          // h1(-1)
#define M_OFF_T0  (M_OFF_H1I + (unsigned long long)SL*2)
#define M_OFF_ST  (M_OFF_T0 + 31ull*3*NHID*4)       // statsP[2 bg][2][1024] f32
// ring: 16 slots x 64 (bg,cg) tiles x 3072 f32; tile = [96 n][32 m]
#define M_OFF_XG  (M_OFF_ST + 16384ull)

// LDS: 2D red = 384*36*4 = 55296; epilogue wsc = 63984
#define LDS_BYTES 65024

__device__ __forceinline__ unsigned short f2bf(float f){
  unsigned u = __builtin_bit_cast(unsigned, f);
  u += 0x7fffu + ((u >> 16) & 1u);               // RNE
  return (unsigned short)(u >> 16);
}
__device__ __forceinline__ float bf2f(unsigned short h){
  unsigned u = ((unsigned)h) << 16;
  return __builtin_bit_cast(float, u);
}
__device__ __forceinline__ float sigm(float x){ return 1.f/(1.f + __expf(-x)); }
__device__ __forceinline__ float tanh_f(float x){ return 1.f - 2.f/(__expf(2.f*x) + 1.f); }

__device__ __forceinline__ void burn(float& d){
#pragma unroll
  for (int i=0;i<16;++i)
    asm volatile("v_fmac_f32 %0, %1, %2" : "+v"(d) : "v"(d), "v"(d));
}

// ---- flag sync ----
__device__ __forceinline__ void setflag(unsigned* f, unsigned v){
  __hip_atomic_store(f, v, __ATOMIC_RELAXED, __HIP_MEMORY_SCOPE_AGENT);
}
// R9: PER-WAVE wait on the 4 producer flags this wave's K-slice needs.
// Wave w reads slab cols [w*128,(w+1)*128) = producers cg=4w..4w+3 only.
// Waiting per-wave (instead of WG-wide on all 32) lets fast waves start
// their loads+MFMAs while a straggling producer delays only its consumer
// wave; the LDS-reduce barrier re-synchronizes afterward.
__device__ __forceinline__ void waitflags4(const unsigned* f, int base4, int target, int lane, float& d){
  const unsigned* p = f + (size_t)(base4 + (lane & 3))*16;
  for(;;){
    int v = (int)__hip_atomic_load(p, __ATOMIC_RELAXED, __HIP_MEMORY_SCOPE_AGENT);
    if (__all(v >= target)) break;
    burn(d);
  }
  asm volatile("" ::: "memory");   // block hoisting dependent loads above the wait
}
__device__ __forceinline__ void waitflag1(const unsigned* f, int idx, int target, float& d){
  const unsigned* p = f + (size_t)idx*16;
  while ((int)__hip_atomic_load(p, __ATOMIC_RELAXED, __HIP_MEMORY_SCOPE_AGENT) < target)
    burn(d);
  asm volatile("" ::: "memory");
}
__device__ __forceinline__ void waitflag1_slow(const unsigned* f, int idx, int target, float& d){
  const unsigned* p = f + (size_t)idx*16;
  while ((int)__hip_atomic_load(p, __ATOMIC_RELAXED, __HIP_MEMORY_SCOPE_AGENT) < target){
    burn(d); burn(d); burn(d); burn(d);
  }
  asm volatile("" ::: "memory");
}
__device__ __forceinline__ void sig(unsigned* c){
  __hip_atomic_fetch_add(c, 1u, __ATOMIC_RELAXED, __HIP_MEMORY_SCOPE_AGENT);
}
__device__ __forceinline__ void waitc(unsigned* c, unsigned v, float& d){
  while (__hip_atomic_load(c, __ATOMIC_RELAXED, __HIP_MEMORY_SCOPE_AGENT) < v)
    burn(d);
}

// sc1: write past the non-coherent per-XCD L2 (R4 proved sc0 breaks)
__device__ __forceinline__ void stc16(void* p, short8 v){
  asm volatile("global_store_dwordx4 %0, %1, off sc1"
               :: "v"((unsigned long long)(uintptr_t)p), "v"(v) : "memory");
}
__device__ __forceinline__ void stc4(void* p, float v){
  asm volatile("global_store_dword %0, %1, off sc1"
               :: "v"((unsigned long long)(uintptr_t)p), "v"(v) : "memory");
}
__device__ __forceinline__ void drain_vm(){
  asm volatile("s_waitcnt vmcnt(0)" ::: "memory");
}

// ---- 2D machinery (all roles): WG owns 32 batches x 32 channels ----
// weight B-frags: 6 n-tiles; n-index in red = gate*32 + c32
__device__ __forceinline__ void load_bfrags6(const float* W, int ch0,
                                             short8 (&bfr)[6][4], int lane, int wid)
{
  const int l15 = lane & 15, q = lane >> 4;
#pragma unroll
  for (int nt=0; nt<6; ++nt){
    int grow = (nt>>1)*NHID + ch0 + (nt&1)*16 + l15;
    const float* wp0 = W + (size_t)grow*NHID + wid*128 + q*8;
#pragma unroll
    for (int kt=0; kt<4; ++kt){
      const float* wp = wp0 + kt*32;
      short8 fr;
#pragma unroll
      for (int j=0;j<8;++j) fr[j] = (short)f2bf(wp[j]);
      bfr[nt][kt] = fr;
    }
  }
}
__device__ __forceinline__ void load_a2(const unsigned short* slab, int b0,
                                        short8 (&f)[2][4], int lane, int wid)
{
#pragma unroll
  for (int mt=0;mt<2;++mt){
    const short8* p = (const short8*)(slab + (size_t)(b0 + mt*16 + (lane&15))*NHID
                                      + wid*128 + (lane>>4)*8);
#pragma unroll
    for (int kt=0;kt<4;++kt) f[mt][kt] = p[kt*4];
  }
}
// M=32,N=96,K=1024: 8 waves split K 8-way (wid*128); pair-reduce (w, w+4)
__device__ __forceinline__ void gemm2d(const short8 (&fA)[2][4],
                                       const short8 (&bfr)[6][4],
                                       float* red, int lane, int wid)
{
  const int l15 = lane & 15, q = lane >> 4;
  float4v acc[2][6];
#pragma unroll
  for (int mt=0; mt<2; ++mt)
#pragma unroll
    for (int nt=0; nt<6; ++nt) acc[mt][nt] = (float4v){0.f,0.f,0.f,0.f};
#pragma unroll
  for (int kt=0; kt<4; ++kt){
#pragma unroll
    for (int nt=0; nt<6; ++nt){
      acc[0][nt] = __builtin_amdgcn_mfma_f32_16x16x32_bf16(fA[0][kt], bfr[nt][kt], acc[0][nt],0,0,0);
      acc[1][nt] = __builtin_amdgcn_mfma_f32_16x16x32_bf16(fA[1][kt], bfr[nt][kt], acc[1][nt],0,0,0);
    }
  }
  if (wid >= 4){
#pragma unroll
    for (int mt=0; mt<2; ++mt)
#pragma unroll
      for (int nt=0; nt<6; ++nt){
        int n = nt*16 + l15, row = mt*16 + q*4;
        *(float4v*)(red + ((wid-4)*96 + n)*RS2 + row) = acc[mt][nt];
      }
  }
  __syncthreads();
  if (wid < 4){
#pragma unroll
    for (int mt=0; mt<2; ++mt)
#pragma unroll
      for (int nt=0; nt<6; ++nt){
        int n = nt*16 + l15, row = mt*16 + q*4;
        float4v* p = (float4v*)(red + (wid*96 + n)*RS2 + row);
        float4v v = *p;
        *p = v + acc[mt][nt];
      }
  }
  __syncthreads();
}

__global__ __launch_bounds__(NTHR, 2) void mgru_fused(
    const int*   __restrict__ x,    const float* __restrict__ h0,
    const float* __restrict__ emb,
    const float* __restrict__ Wih0, const float* __restrict__ Whh0,
    const float* __restrict__ bih0, const float* __restrict__ bhh0,
    const float* __restrict__ Wih1, const float* __restrict__ Whh1,
    const float* __restrict__ bih1, const float* __restrict__ bhh1,
    const float* __restrict__ gamma, const float* __restrict__ beta,
    const float* __restrict__ Wout, const float* __restrict__ bout,
    float* __restrict__ out, char* ws)
{
  __shared__ __align__(16) char smem[LDS_BYTES];
  float* red = (float*)smem;

  unsigned* f0  = (unsigned*)(ws + OFF_F0);
  unsigned* f1  = (unsigned*)(ws + OFF_F1);
  unsigned* f2  = (unsigned*)(ws + OFF_F2);
  unsigned* fin = (unsigned*)(ws + OFF_FIN);
  unsigned short* y0b   = (unsigned short*)(ws + M_OFF_Y0);
  unsigned short* y1    = (unsigned short*)(ws + M_OFF_Y1);
  unsigned short* h1i   = (unsigned short*)(ws + M_OFF_H1I);
  float*          T0    = (float*)(ws + M_OFF_T0);
  float*          stats = (float*)(ws + M_OFF_ST);     // [2 bg][2][1024]
  float*          xgring= (float*)(ws + M_OFF_XG);

  const int tid  = threadIdx.x;
  const int lane = tid & 63;
  const int wid  = tid >> 6;
  const int wg   = blockIdx.x;
  const int l15 = lane & 15, q = lane >> 4;
  float dummy = (float)tid * 1e-30f + 1.0f;

  if (wg >= NWRK){
    // heater: keep clocks boosted; then join epilogue
    for(;;){
      for (int i=0;i<64;++i) burn(dummy);
      unsigned v = __hip_atomic_load(fin, __ATOMIC_RELAXED, __HIP_MEMORY_SCOPE_AGENT);
      if (v >= (unsigned)NWRK) break;
    }
    if (tid == 0) __threadfence();          // acquire
    __syncthreads();
    if (dummy == 1234.5678f) ((volatile float*)smem)[0] = dummy;
    goto epilogue;
  }

  {
    // one-time acquire
    if (tid == 0) __threadfence();
    __syncthreads();

    const int role = (wg < 64) ? 0 : (wg < 128 ? 1 : 2);

    if (role == 0){
      // ====== layer-0 chain, 2D: WG(bg,cg) owns 32 batches x 32 ch ======
      const int rw = wg, bg = rw >> 5, cg = rw & 31;
      const int b0 = bg*32, ch0 = cg*32;
      const int fidx = bg*32 + cg;
      const int g = tid;                 // gate thread id (tid<128)
      const int b = b0 + (g & 31);
      const int oct = g >> 5;            // 0..3 -> 8-channel octet
      short8 bfr0[6][4];
      float hprev[8] = {0,0,0,0,0,0,0,0};
      float br[8], bz[8], bn[8];

      if (tid < 128){
        short8 pk;
#pragma unroll
        for (int j=0;j<8;++j){
          int ch = ch0 + oct*8 + j;
          hprev[j] = h0[(size_t)b*NHID + ch];
          br[j] = bhh0[ch]; bz[j] = bhh0[NHID + ch]; bn[j] = bhh0[2*NHID + ch];
          pk[j] = (short)f2bf(hprev[j]);
        }
        stc16(y0b + (size_t)b*NHID + ch0 + oct*8, pk);   // slot0 = y0(-1)
        drain_vm();
      }
      __syncthreads();
      if (tid == 0) setflag(f0 + (size_t)fidx*16, 1u);

      // T0 slice: this WG's 96 gate-channels (idempotent across bg dup)
      for (int e = tid; e < NVOC*96; e += NTHR){
        int v = e / 96, n = e - v*96;
        int gate = n >> 5, c32 = n & 31;
        int grow = gate*NHID + ch0 + c32;
        const float4v* e4 = (const float4v*)(emb  + (size_t)v*NHID);
        const float4v* w4 = (const float4v*)(Wih0 + (size_t)grow*NHID);
        float acc = 0.f;
        for (int k=0;k<NHID/4;++k){
          float4v a = e4[k], bb = w4[k];
          acc += a[0]*bb[0] + a[1]*bb[1] + a[2]*bb[2] + a[3]*bb[3];
        }
        T0[(size_t)v*3*NHID + grow] = acc + bih0[grow];
      }
      load_bfrags6(Whh0, ch0, bfr0, lane, wid);
      __syncthreads();

      for (int t = 0; t < NSEQ; ++t){
        // per-wave: wait only this wave's 4 K-slice producers
        waitflags4(f0, bg*32 + wid*4, t+1, lane, dummy);
        short8 fA[2][4];
        load_a2(y0b + (size_t)t*SL, b0, fA, lane, wid);
        gemm2d(fA, bfr0, red, lane, wid);
        if (tid < 128){
          int tok = x[(size_t)b*NSEQ + t];
          const float* tp = T0 + (size_t)tok*3*NHID;
          int m = g & 31;
          short8 pk;
#pragma unroll
          for (int j=0;j<8;++j){
            int c32 = oct*8 + j, ch = ch0 + c32;
            float hr = br[j], hz = bz[j], hn = bn[j];
#pragma unroll
            for (int w=0;w<4;++w){
              hr += red[(w*96 +      c32)*RS2 + m];
              hz += red[(w*96 + 32 + c32)*RS2 + m];
              hn += red[(w*96 + 64 + c32)*RS2 + m];
            }
            float r = sigm(tp[ch] + hr);
            float z = sigm(tp[NHID + ch] + hz);
            float n = tanh_f(tp[2*NHID + ch] + r*hn);
            float hnv = (1.f - z)*n + z*hprev[j];
            hprev[j] = hnv;
            pk[j] = (short)f2bf(hnv);
          }
          stc16(y0b + (size_t)(t+1)*SL + (size_t)b*NHID + ch0 + oct*8, pk);
          drain_vm();
        }
        __syncthreads();
        if (tid == 0) setflag(f0 + (size_t)fidx*16, (unsigned)(t+2));
      }

    } else if (role == 1){
      // ====== xg producer, 2D: WG(bg,cg) computes the exact tile its
      // role2 counterpart consumes; bit-exact K-split/order preserved.
      const int rw = wg - 64, bg = rw >> 5, cg = rw & 31;
      const int b0 = bg*32, ch0 = cg*32;
      const int fidx = bg*32 + cg;
      short8 wf[6][4];
      load_bfrags6(Wih1, ch0, wf, lane, wid);
      __syncthreads();

      for (int t = 0; t < NSEQ; ++t){
        if ((t & 3) == 0 && t >= 16)
          waitflag1_slow(f2, fidx, t-11, dummy);    // ring WAR guard vs counterpart
        waitflags4(f0, bg*32 + wid*4, t+2, lane, dummy);  // y0(t) K-slice ready
        short8 fB[2][4];
        load_a2(y0b + (size_t)(t+1)*SL, b0, fB, lane, wid);
        gemm2d(fB, wf, red, lane, wid);
        // publish tile [96 n][32 m]: bias-first then w=0..3 (bit-exact)
        float* xgw = xgring + ((size_t)(t & (XG_SLOTS-1))*64 + (size_t)fidx)*3072;
#pragma unroll
        for (int i=0;i<6;++i){
          int idx = tid + i*512;           // 0..3071 = n*32 + m
          int n = idx >> 5, m = idx & 31;
          float v = bih1[(n>>5)*NHID + ch0 + (n&31)];
          v += red[(      n)*RS2 + m];
          v += red[( 96 + n)*RS2 + m];
          v += red[(192 + n)*RS2 + m];
          v += red[(288 + n)*RS2 + m];
          stc4(xgw + idx, v);
        }
        drain_vm();
        __syncthreads();                   // red reads done; WAR safe for next gemm
        if (tid == 0) setflag(f1 + (size_t)fidx*16, (unsigned)(t+2));
      }

    } else {
      // ====== layer-1 chain, 2D: single gemm on the critical path ======
      const int rw = wg - 128, bg = rw >> 5, cg = rw & 31;
      const int b0 = bg*32, ch0 = cg*32;
      const int fidx = bg*32 + cg;
      const int g = tid;
      const int b = b0 + (g & 31);
      const int oct = g >> 5;
      short8 bfrH[6][4];
      float hprev[8] = {0,0,0,0,0,0,0,0};
      float bhr[8], bhz[8], bhn[8];
      float s1[8] = {0,0,0,0,0,0,0,0}, s2[8] = {0,0,0,0,0,0,0,0};

      if (tid < 128){
        short8 pk;
#pragma unroll
        for (int j=0;j<8;++j){
          int ch = ch0 + oct*8 + j;
          hprev[j] = h0[(size_t)NB*NHID + (size_t)b*NHID + ch];
          bhr[j] = bhh1[ch]; bhz[j] = bhh1[NHID + ch]; bhn[j] = bhh1[2*NHID + ch];
          pk[j] = (short)f2bf(hprev[j]);
        }
        stc16(h1i + (size_t)b*NHID + ch0 + oct*8, pk);
        drain_vm();
      }
      __syncthreads();
      if (tid == 0) setflag(f2 + (size_t)fidx*16, 1u);

      load_bfrags6(Whh1, ch0, bfrH, lane, wid);
      __syncthreads();

      for (int t = 0; t < NSEQ; ++t){
        // per-wave: wait only this wave's 4 K-slice producers
        waitflags4(f2, bg*32 + wid*4, t+1, lane, dummy);
        const unsigned short* hsrc = (t == 0) ? h1i : (y1 + (size_t)(t-1)*SL);
        short8 fH[2][4];
        load_a2(hsrc, b0, fH, lane, wid);
        gemm2d(fH, bfrH, red, lane, wid);
        float hrv[8], hzv[8], hnv_[8];
        if (tid < 128){
          int m = g & 31;
#pragma unroll
          for (int j=0;j<8;++j){
            int c32 = oct*8 + j;
            float hr = bhr[j], hz = bhz[j], hn = bhn[j];
#pragma unroll
            for (int w=0;w<4;++w){
              hr += red[(w*96 +      c32)*RS2 + m];
              hz += red[(w*96 + 32 + c32)*RS2 + m];
              hn += red[(w*96 + 64 + c32)*RS2 + m];
            }
            hrv[j] = hr; hzv[j] = hz; hnv_[j] = hn;
          }
        }
        waitflag1(f1, fidx, t+2, dummy);            // xg(t) tile from counterpart
        if (tid < 128){
          const float* xgt = xgring + ((size_t)(t & (XG_SLOTS-1))*64 + (size_t)fidx)*3072;
          int m = g & 31;
          short8 pk;
#pragma unroll
          for (int j=0;j<8;++j){
            int c32 = oct*8 + j;
            float xr = __hip_atomic_load(xgt + (size_t)(     c32)*32 + m, __ATOMIC_RELAXED, __HIP_MEMORY_SCOPE_AGENT);
            float xz = __hip_atomic_load(xgt + (size_t)(32 + c32)*32 + m, __ATOMIC_RELAXED, __HIP_MEMORY_SCOPE_AGENT);
            float xn = __hip_atomic_load(xgt + (size_t)(64 + c32)*32 + m, __ATOMIC_RELAXED, __HIP_MEMORY_SCOPE_AGENT);
            float r  = sigm(xr + hrv[j]);
            float z  = sigm(xz + hzv[j]);
            float nn = tanh_f(xn + r*hnv_[j]);
            float hnew = (1.f - z)*nn + z*hprev[j];
            hprev[j] = hnew;
            unsigned short hb = f2bf(hnew);
            pk[j] = (short)hb;
            float hq = bf2f(hb);
            s1[j] += hq; s2[j] += hq*hq;
          }
          stc16(y1 + (size_t)t*SL + (size_t)b*NHID + ch0 + oct*8, pk);
          drain_vm();
        }
        __syncthreads();
        if (tid == 0) setflag(f2 + (size_t)fidx*16, (unsigned)(t+2));
      }

      // BN stats: per-channel sums over this WG's 32 batches (ascending i),
      // cross-bg summed ascending in epilogue -> bit-identical fold order.
      {
        float* sb = (float*)smem;
        __syncthreads();
        if (tid < 128){
#pragma unroll
          for (int j=0;j<8;++j) sb[(oct*8 + j)*32 + (g & 31)] = s1[j];
        }
        __syncthreads();
        if (tid < 32){
          float a = 0.f;
          for (int i=0;i<32;++i) a += sb[tid*32 + i];
          stats[(size_t)bg*2048 + ch0 + tid] = a;
        }
        __syncthreads();
        if (tid < 128){
#pragma unroll
          for (int j=0;j<8;++j) sb[(oct*8 + j)*32 + (g & 31)] = s2[j];
        }
        __syncthreads();
        if (tid < 32){
          float a = 0.f;
          for (int i=0;i<32;++i) a += sb[tid*32 + i];
          stats[(size_t)bg*2048 + 1024 + ch0 + tid] = a;
        }
      }
    }

    // ======== fin barrier with ONE wbL2/inv fence pair per WG ========
    __syncthreads();
    if (tid == 0){
      __threadfence();          // release (y1 sc1 + stats plain -> L2 wb)
      sig(fin);
      waitc(fin, NWRK, dummy);
      __threadfence();          // acquire
    }
    __syncthreads();
    if (dummy == 1234.5678f) ((volatile float*)smem)[0] = dummy;
  }

epilogue:
  // ============ epilogue: fold BN into Wout, GEMM -> out ============
  {
    const float inv_n = 1.f/32768.f;

    float* bpart    = (float*)smem;
    float* bprime_l = (float*)(smem + 2048);
    {
      int v = tid >> 4, k0 = tid & 15;
      float partial = 0.f;
      if (v < NVOC){
        for (int k = k0; k < NHID; k += 16){
          float s1k = stats[k] + stats[2048 + k];
          float s2k = stats[1024 + k] + stats[3072 + k];
          float mu  = s1k*inv_n;
          float var = s2k*inv_n - mu*mu;
          float sc  = gamma[k]*rsqrtf(var + EPSV);
          partial += (beta[k] - mu*sc) * Wout[(size_t)v*NHID + k];
        }
      }
      bpart[tid] = partial;
    }
    __syncthreads();
    if (tid < 32){
      float bpv = 0.f;
      for (int j=0;j<16;++j) bpv += bpart[tid*16 + j];
      bprime_l[tid] = (tid < NVOC) ? (bpv + bout[tid]) : 0.f;
    }
    __syncthreads();
    float bp_a = bprime_l[l15];
    float bp_b = (l15 < 15) ? bprime_l[16 + l15] : 0.f;
    __syncthreads();

    unsigned short* wsc = (unsigned short*)smem;   // [31][1032] bf16
    for (int e = tid; e < NVOC*1032; e += NTHR){
      int v = e / 1032, k = e - v*1032;
      float val = 0.f;
      if (k < NHID){
        float s1k = stats[k] + stats[2048 + k];
        float s2k = stats[1024 + k] + stats[3072 + k];
        float mu  = s1k*inv_n;
        float var = s2k*inv_n - mu*mu;
        float sc  = gamma[k]*rsqrtf(var + EPSV);
        val = Wout[(size_t)v*NHID + k] * sc;
      }
      wsc[e] = f2bf(val);
    }
    __syncthreads();

    unsigned short* y1b = (unsigned short*)(ws + M_OFF_Y1);
    int wglob = wg*8 + wid;                 // 0..2047
    if ((wglob & 3) == 0){
      int J = wglob >> 2;                   // 0..511
      float4v acc[4][2];
#pragma unroll
      for (int mt=0;mt<4;++mt){ acc[mt][0] = (float4v){0,0,0,0}; acc[mt][1] = (float4v){0,0,0,0}; }
      const unsigned short* abase = y1b + (size_t)(J*64 + l15)*NHID + q*8;
      const short8 zero8 = (short8){0,0,0,0,0,0,0,0};
#pragma unroll 4
      for (int kt=0; kt<32; ++kt){
        short8 bv0 = *(const short8*)(wsc + (size_t)l15*1032 + kt*32 + q*8);
        short8 bv1 = (l15 < 15) ? *(const short8*)(wsc + (size_t)(16+l15)*1032 + kt*32 + q*8) : zero8;
        short8 a0 = *(const short8*)(abase + (size_t)kt*32);
        short8 a1 = *(const short8*)(abase + 16*NHID + (size_t)kt*32);
        short8 a2 = *(const short8*)(abase + 32*NHID + (size_t)kt*32);
        short8 a3 = *(const short8*)(abase + 48*NHID + (size_t)kt*32);
        acc[0][0] = __builtin_amdgcn_mfma_f32_16x16x32_bf16(a0, bv0, acc[0][0],0,0,0);
        acc[1][0] = __builtin_amdgcn_mfma_f32_16x16x32_bf16(a1, bv0, acc[1][0],0,0,0);
        acc[2][0] = __builtin_amdgcn_mfma_f32_16x16x32_bf16(a2, bv0, acc[2][0],0,0,0);
        acc[3][0] = __builtin_amdgcn_mfma_f32_16x16x32_bf16(a3, bv0, acc[3][0],0,0,0);
        acc[0][1] = __builtin_amdgcn_mfma_f32_16x16x32_bf16(a0, bv1, acc[0][1],0,0,0);
        acc[1][1] = __builtin_amdgcn_mfma_f32_16x16x32_bf16(a1, bv1, acc[1][1],0,0,0);
        acc[2][1] = __builtin_amdgcn_mfma_f32_16x16x32_bf16(a2, bv1, acc[2][1],0,0,0);
        acc[3][1] = __builtin_amdgcn_mfma_f32_16x16x32_bf16(a3, bv1, acc[3][1],0,0,0);
      }
#pragma unroll
      for (int mt=0;mt<4;++mt){
#pragma unroll
        for (int nt=0;nt<2;++nt){
          int v = nt*16 + l15;
          if (v < NVOC){
            float bpv = (nt==0) ? bp_a : bp_b;
            int r0 = J*64 + mt*16 + q*4;
#pragma unroll
            for (int i2=0;i2<4;++i2){
              int r = r0 + i2;
              int bb = r & 63, tt = r >> 6;
              out[(size_t)(bb*NSEQ + tt)*NVOC + v] = acc[mt][nt][i2] + bpv;
            }
          }
        }
      }
    }
  }
}

extern "C" void kernel_launch(void* const* d_in, const int* in_sizes, int n_in,
                              void* d_out, int out_size, void* d_ws, size_t ws_size,
                              hipStream_t stream) {
  (void)in_sizes; (void)n_in; (void)out_size; (void)ws_size;
  hipMemsetAsync(d_ws, 0, CNT_BYTES, stream);   // zero flags + fin counter
  mgru_fused<<<dim3(NGRID), dim3(NTHR), 0, stream>>>(
      (const int*)d_in[0],  (const float*)d_in[1],  (const float*)d_in[2],
      (const float*)d_in[3], (const float*)d_in[4], (const float*)d_in[5],
      (const float*)d_in[6], (const float*)d_in[7], (const float*)d_in[8],
      (const float*)d_in[9], (const float*)d_in[10], (const float*)d_in[11],
      (const float*)d_in[12], (const float*)d_in[13], (const float*)d_in[14],
      (float*)d_out, (char*)d_ws);
}